// Round 1
// baseline (2563.634 us; speedup 1.0000x reference)
//
#include <hip/hip_runtime.h>
#include <math.h>

#define S_LEN 2048
#define DMODEL 1024
#define NHEADS 16
#define DK 64

// ---------------------------------------------------------------------------
// GEMM: Y = X[M,K] @ W[K,N] + bias[N]
// mode 0: scatter output to [B, H, S, dk] layout (for q/k/v projections)
// mode 1: plain row-major [M, N] (for output projection)
// Tile: 64x64, BK=16, 256 threads, each thread computes 4x4.
// ---------------------------------------------------------------------------
__global__ __launch_bounds__(256)
void gemm_bias_kernel(const float* __restrict__ X, const float* __restrict__ W,
                      const float* __restrict__ bias, float* __restrict__ Y,
                      int M, int N, int K, int mode)
{
    __shared__ float As[16][65];   // [k][m], padded to dodge store conflicts
    __shared__ float Bs[16][64];   // [k][n]

    const int tid = threadIdx.x;
    const int tx = tid & 15;       // 0..15 -> n
    const int ty = tid >> 4;       // 0..15 -> m
    const int bm = blockIdx.x * 64;
    const int bn = blockIdx.y * 64;

    const int arow = tid >> 2;           // 0..63
    const int akq  = (tid & 3) * 4;      // 0,4,8,12
    const int brow = tid >> 4;           // 0..15
    const int bnq  = (tid & 15) * 4;     // 0..60

    float acc[4][4];
    #pragma unroll
    for (int i = 0; i < 4; ++i)
        #pragma unroll
        for (int j = 0; j < 4; ++j) acc[i][j] = 0.f;

    for (int k0 = 0; k0 < K; k0 += 16) {
        float4 av = *reinterpret_cast<const float4*>(
            X + (size_t)(bm + arow) * K + k0 + akq);
        As[akq + 0][arow] = av.x;
        As[akq + 1][arow] = av.y;
        As[akq + 2][arow] = av.z;
        As[akq + 3][arow] = av.w;
        float4 bv = *reinterpret_cast<const float4*>(
            W + (size_t)(k0 + brow) * N + bn + bnq);
        *reinterpret_cast<float4*>(&Bs[brow][bnq]) = bv;
        __syncthreads();

        #pragma unroll
        for (int kk = 0; kk < 16; ++kk) {
            float a0 = As[kk][ty * 4 + 0];
            float a1 = As[kk][ty * 4 + 1];
            float a2 = As[kk][ty * 4 + 2];
            float a3 = As[kk][ty * 4 + 3];
            float b0 = Bs[kk][tx * 4 + 0];
            float b1 = Bs[kk][tx * 4 + 1];
            float b2 = Bs[kk][tx * 4 + 2];
            float b3 = Bs[kk][tx * 4 + 3];
            acc[0][0] += a0 * b0; acc[0][1] += a0 * b1; acc[0][2] += a0 * b2; acc[0][3] += a0 * b3;
            acc[1][0] += a1 * b0; acc[1][1] += a1 * b1; acc[1][2] += a1 * b2; acc[1][3] += a1 * b3;
            acc[2][0] += a2 * b0; acc[2][1] += a2 * b1; acc[2][2] += a2 * b2; acc[2][3] += a2 * b3;
            acc[3][0] += a3 * b0; acc[3][1] += a3 * b1; acc[3][2] += a3 * b2; acc[3][3] += a3 * b3;
        }
        __syncthreads();
    }

    #pragma unroll
    for (int i = 0; i < 4; ++i) {
        const int m = bm + ty * 4 + i;
        #pragma unroll
        for (int j = 0; j < 4; ++j) {
            const int n = bn + tx * 4 + j;
            float val = acc[i][j] + bias[n];
            if (mode == 0) {
                // [B*S, D] element (m, n) -> q[b][h][s][d]
                const int b = m >> 11;          // m / S_LEN
                const int s = m & (S_LEN - 1);
                const int h = n >> 6;           // n / DK
                const int d = n & (DK - 1);
                Y[(((size_t)b * NHEADS + h) * S_LEN + s) * DK + d] = val;
            } else {
                Y[(size_t)m * N + n] = val;
            }
        }
    }
}

// ---------------------------------------------------------------------------
// Flash-style attention. q,k,v: [B,H,S,DK] fp32. o: [B,S,DMODEL] fp32.
// One thread owns one q row end-to-end: q row + O accumulator in registers,
// K/V tiles (16 x 64) staged in LDS; all LDS reads are wave-uniform
// broadcasts (conflict-free). Online softmax per thread (no cross-lane).
// ---------------------------------------------------------------------------
__global__ __launch_bounds__(256)
void attn_kernel(const float* __restrict__ q, const float* __restrict__ k,
                 const float* __restrict__ v, float* __restrict__ o)
{
    __shared__ float Kt[16][64];
    __shared__ float Vt[16][64];

    const int tid = threadIdx.x;
    const int bh = blockIdx.y;                  // b*NHEADS + h, 0..31
    const int qrow = blockIdx.x * 256 + tid;    // 0..2047
    const size_t head_base = (size_t)bh * S_LEN * DK;

    // load q row into registers (16 x float4)
    float qreg[64];
    const float* qp = q + head_base + (size_t)qrow * DK;
    #pragma unroll
    for (int i = 0; i < 16; ++i) {
        float4 t = reinterpret_cast<const float4*>(qp)[i];
        qreg[i * 4 + 0] = t.x; qreg[i * 4 + 1] = t.y;
        qreg[i * 4 + 2] = t.z; qreg[i * 4 + 3] = t.w;
    }

    float mrun = -INFINITY, lrun = 0.f;
    float O[64];
    #pragma unroll
    for (int i = 0; i < 64; ++i) O[i] = 0.f;

    const float scale = 0.125f;  // 1/sqrt(64)

    for (int kt = 0; kt < S_LEN; kt += 16) {
        // stage K,V tile: 16 rows x 64 dims = 1024 floats each; contiguous.
        const float* kp = k + head_base + (size_t)kt * DK;
        const float* vp = v + head_base + (size_t)kt * DK;
        float4 kv4 = reinterpret_cast<const float4*>(kp)[tid];
        float4 vv4 = reinterpret_cast<const float4*>(vp)[tid];
        reinterpret_cast<float4*>(&Kt[0][0])[tid] = kv4;
        reinterpret_cast<float4*>(&Vt[0][0])[tid] = vv4;
        __syncthreads();

        // scores for this tile
        float s[16];
        #pragma unroll
        for (int kc = 0; kc < 16; ++kc) {
            float acc = 0.f;
            #pragma unroll
            for (int d = 0; d < 64; ++d) acc += qreg[d] * Kt[kc][d];
            s[kc] = acc * scale;
        }

        float tmax = s[0];
        #pragma unroll
        for (int kc = 1; kc < 16; ++kc) tmax = fmaxf(tmax, s[kc]);
        const float m_new = fmaxf(mrun, tmax);
        const float corr = __expf(mrun - m_new);

        float p[16];
        float tsum = 0.f;
        #pragma unroll
        for (int kc = 0; kc < 16; ++kc) {
            p[kc] = __expf(s[kc] - m_new);
            tsum += p[kc];
        }
        lrun = lrun * corr + tsum;
        mrun = m_new;

        #pragma unroll
        for (int d = 0; d < 64; ++d) O[d] *= corr;
        #pragma unroll
        for (int kc = 0; kc < 16; ++kc) {
            #pragma unroll
            for (int d = 0; d < 64; ++d) O[d] += p[kc] * Vt[kc][d];
        }
        __syncthreads();
    }

    const float inv_l = 1.f / lrun;
    const int b = bh >> 4;
    const int h = bh & (NHEADS - 1);
    float* op = o + ((size_t)(b * S_LEN + qrow)) * DMODEL + h * DK;
    #pragma unroll
    for (int i = 0; i < 16; ++i) {
        float4 t;
        t.x = O[i * 4 + 0] * inv_l;
        t.y = O[i * 4 + 1] * inv_l;
        t.z = O[i * 4 + 2] * inv_l;
        t.w = O[i * 4 + 3] * inv_l;
        reinterpret_cast<float4*>(op)[i] = t;
    }
}

// ---------------------------------------------------------------------------
extern "C" void kernel_launch(void* const* d_in, const int* in_sizes, int n_in,
                              void* d_out, int out_size, void* d_ws, size_t ws_size,
                              hipStream_t stream)
{
    const float* Q  = (const float*)d_in[0];
    const float* K  = (const float*)d_in[1];
    const float* V  = (const float*)d_in[2];
    const float* Wq = (const float*)d_in[3];
    const float* bq = (const float*)d_in[4];
    const float* Wk = (const float*)d_in[5];
    const float* bk = (const float*)d_in[6];
    const float* Wv = (const float*)d_in[7];
    const float* bv = (const float*)d_in[8];
    const float* Wo = (const float*)d_in[9];
    const float* bo = (const float*)d_in[10];
    float* out = (float*)d_out;

    // workspace: 4 buffers of B*S*D floats (16 MB each, 64 MB total)
    float* ws = (float*)d_ws;
    const size_t BUF = (size_t)4 * 1024 * 1024;
    float* qb = ws;
    float* kb = ws + BUF;
    float* vb = ws + 2 * BUF;
    float* ob = ws + 3 * BUF;

    const int M = 2 * S_LEN;   // 4096
    const int N = DMODEL;      // 1024
    const int Kd = DMODEL;     // 1024

    dim3 gemm_grid(M / 64, N / 64);   // 64 x 16
    dim3 gemm_blk(256);

    gemm_bias_kernel<<<gemm_grid, gemm_blk, 0, stream>>>(Q, Wq, bq, qb, M, N, Kd, 0);
    gemm_bias_kernel<<<gemm_grid, gemm_blk, 0, stream>>>(K, Wk, bk, kb, M, N, Kd, 0);
    gemm_bias_kernel<<<gemm_grid, gemm_blk, 0, stream>>>(V, Wv, bv, vb, M, N, Kd, 0);

    attn_kernel<<<dim3(S_LEN / 256, 2 * NHEADS), 256, 0, stream>>>(qb, kb, vb, ob);

    gemm_bias_kernel<<<gemm_grid, gemm_blk, 0, stream>>>(ob, Wo, bo, out, M, N, Kd, 1);
}

// Round 3
// 746.427 us; speedup vs baseline: 3.4345x; 3.4345x over previous
//
#include <hip/hip_runtime.h>
#include <hip/hip_bf16.h>
#include <math.h>

#define S_LEN 2048
#define DMODEL 1024
#define NHEADS 16
#define DK 64

typedef __attribute__((ext_vector_type(8))) short bf16x8;
typedef __attribute__((ext_vector_type(4))) float f32x4;

static __device__ __forceinline__ unsigned short f2bf(float f) {
    unsigned u = __builtin_bit_cast(unsigned, f);
    u = (u + 0x7fffu + ((u >> 16) & 1u)) >> 16;   // RTN-even
    return (unsigned short)u;
}

// ---------------------------------------------------------------------------
// GEMM: Y = X[M,K] @ W[K,N] + bias[N]   (fp32 compute)
// mode 0: bf16 out, scaled 1/8, layout [bh][s][dk]       (q projection)
// mode 1: bf16 out,             layout [bh][s][dk]       (k projection)
// mode 2: bf16 out,             layout [bh][dk][s]  (V TRANSPOSED)
// mode 3: fp32 out, row-major [M,N]                      (output projection)
// ---------------------------------------------------------------------------
__global__ __launch_bounds__(256)
void gemm_bias_kernel(const float* __restrict__ X, const float* __restrict__ W,
                      const float* __restrict__ bias, void* __restrict__ Y,
                      int M, int N, int K, int mode)
{
    __shared__ float As[16][65];
    __shared__ float Bs[16][64];

    const int tid = threadIdx.x;
    const int tx = tid & 15;
    const int ty = tid >> 4;
    const int bm = blockIdx.x * 64;
    const int bn = blockIdx.y * 64;

    const int arow = tid >> 2;
    const int akq  = (tid & 3) * 4;
    const int brow = tid >> 4;
    const int bnq  = (tid & 15) * 4;

    float acc[4][4];
    #pragma unroll
    for (int i = 0; i < 4; ++i)
        #pragma unroll
        for (int j = 0; j < 4; ++j) acc[i][j] = 0.f;

    for (int k0 = 0; k0 < K; k0 += 16) {
        float4 av = *reinterpret_cast<const float4*>(
            X + (size_t)(bm + arow) * K + k0 + akq);
        As[akq + 0][arow] = av.x;
        As[akq + 1][arow] = av.y;
        As[akq + 2][arow] = av.z;
        As[akq + 3][arow] = av.w;
        float4 bv = *reinterpret_cast<const float4*>(
            W + (size_t)(k0 + brow) * N + bn + bnq);
        *reinterpret_cast<float4*>(&Bs[brow][bnq]) = bv;
        __syncthreads();

        #pragma unroll
        for (int kk = 0; kk < 16; ++kk) {
            float a0 = As[kk][ty * 4 + 0];
            float a1 = As[kk][ty * 4 + 1];
            float a2 = As[kk][ty * 4 + 2];
            float a3 = As[kk][ty * 4 + 3];
            float b0 = Bs[kk][tx * 4 + 0];
            float b1 = Bs[kk][tx * 4 + 1];
            float b2 = Bs[kk][tx * 4 + 2];
            float b3 = Bs[kk][tx * 4 + 3];
            acc[0][0] += a0 * b0; acc[0][1] += a0 * b1; acc[0][2] += a0 * b2; acc[0][3] += a0 * b3;
            acc[1][0] += a1 * b0; acc[1][1] += a1 * b1; acc[1][2] += a1 * b2; acc[1][3] += a1 * b3;
            acc[2][0] += a2 * b0; acc[2][1] += a2 * b1; acc[2][2] += a2 * b2; acc[2][3] += a2 * b3;
            acc[3][0] += a3 * b0; acc[3][1] += a3 * b1; acc[3][2] += a3 * b2; acc[3][3] += a3 * b3;
        }
        __syncthreads();
    }

    #pragma unroll
    for (int i = 0; i < 4; ++i) {
        const int m = bm + ty * 4 + i;
        #pragma unroll
        for (int j = 0; j < 4; ++j) {
            const int n = bn + tx * 4 + j;
            float val = acc[i][j] + bias[n];
            if (mode == 3) {
                ((float*)Y)[(size_t)m * N + n] = val;
            } else {
                const int b = m >> 11;
                const int s = m & (S_LEN - 1);
                const int h = n >> 6;
                const int d = n & (DK - 1);
                size_t idx;
                if (mode == 2)
                    idx = ((size_t)(b * NHEADS + h) * DK + d) * S_LEN + s;
                else
                    idx = ((size_t)(b * NHEADS + h) * S_LEN + s) * DK + d;
                float v2 = (mode == 0) ? val * 0.125f : val;
                ((unsigned short*)Y)[idx] = f2bf(v2);
            }
        }
    }
}

// ---------------------------------------------------------------------------
// MFMA flash attention.
//   qb: bf16 [bh][s][64]  (pre-scaled by 1/sqrt(dk))
//   kb: bf16 [bh][s][64]
//   vt: bf16 [bh][64][s]  (V transposed)
//   o : fp32 [b][s][1024]
// Block = 256 threads = 4 independent waves; wave owns 16 q rows.
// Swapped QK^T:  S^T = K_tile (A) * Q^T (B)  -> lane holds S^T[kv][q=l&15]
// PV (swapped):  O^T = V^T (A) * P^T (B)     -> lane holds O^T[d][q=l&15]
// P crosses via a per-wave LDS buffer (no barriers anywhere).
// ---------------------------------------------------------------------------
__global__ __launch_bounds__(256)
void attn_mfma_kernel(const unsigned short* __restrict__ qb,
                      const unsigned short* __restrict__ kb,
                      const unsigned short* __restrict__ vt,
                      float* __restrict__ o)
{
    __shared__ unsigned short Pl[4][16][72];   // per-wave P buffer, padded

    const int tid = threadIdx.x;
    const int w = tid >> 6;        // wave in block
    const int l = tid & 63;        // lane
    const int a = l & 15;
    const int g = l >> 4;
    const int bh = blockIdx.y;
    const int q0 = blockIdx.x * 64 + w * 16;

    const unsigned short* qhead = qb + (size_t)bh * S_LEN * DK;
    const unsigned short* khead = kb + (size_t)bh * S_LEN * DK;
    const unsigned short* vhead = vt + (size_t)bh * DK * S_LEN;

    // Q B-fragments: lane holds Q[q0+a][32c + 8g + j], j=0..7 (contiguous)
    bf16x8 qf0 = *reinterpret_cast<const bf16x8*>(qhead + (size_t)(q0 + a) * DK + 8 * g);
    bf16x8 qf1 = *reinterpret_cast<const bf16x8*>(qhead + (size_t)(q0 + a) * DK + 32 + 8 * g);

    f32x4 oacc[4];
    #pragma unroll
    for (int t = 0; t < 4; ++t) oacc[t] = (f32x4){0.f, 0.f, 0.f, 0.f};
    float mrun = -INFINITY;
    float lrun = 0.f;
    const float L2E = 1.44269504f;

    for (int kt = 0; kt < S_LEN; kt += 64) {
        // ---- QK^T: 4 S^T tiles (kv blocks of 16) x 2 K-chunks of 32 ----
        f32x4 sacc[4];
        #pragma unroll
        for (int T = 0; T < 4; ++T) sacc[T] = (f32x4){0.f, 0.f, 0.f, 0.f};
        #pragma unroll
        for (int T = 0; T < 4; ++T) {
            const unsigned short* kp = khead + (size_t)(kt + 16 * T + a) * DK + 8 * g;
            bf16x8 k0 = *reinterpret_cast<const bf16x8*>(kp);
            bf16x8 k1 = *reinterpret_cast<const bf16x8*>(kp + 32);
            sacc[T] = __builtin_amdgcn_mfma_f32_16x16x32_bf16(k0, qf0, sacc[T], 0, 0, 0);
            sacc[T] = __builtin_amdgcn_mfma_f32_16x16x32_bf16(k1, qf1, sacc[T], 0, 0, 0);
        }

        // ---- online softmax over kv for q-column (l&15) ----
        float vmax = -INFINITY;
        #pragma unroll
        for (int T = 0; T < 4; ++T)
            #pragma unroll
            for (int r = 0; r < 4; ++r) vmax = fmaxf(vmax, sacc[T][r]);
        vmax = fmaxf(vmax, __shfl_xor(vmax, 16));
        vmax = fmaxf(vmax, __shfl_xor(vmax, 32));
        const float mnew = fmaxf(mrun, vmax);
        const float corr = exp2f((mrun - mnew) * L2E);

        float p[4][4];
        float ts = 0.f;
        #pragma unroll
        for (int T = 0; T < 4; ++T)
            #pragma unroll
            for (int r = 0; r < 4; ++r) {
                float e = exp2f((sacc[T][r] - mnew) * L2E);
                p[T][r] = e;
                ts += e;
            }
        ts += __shfl_xor(ts, 16);
        ts += __shfl_xor(ts, 32);
        lrun = lrun * corr + ts;
        mrun = mnew;

        #pragma unroll
        for (int t = 0; t < 4; ++t) {
            oacc[t][0] *= corr; oacc[t][1] *= corr;
            oacc[t][2] *= corr; oacc[t][3] *= corr;
        }

        // ---- P -> per-wave LDS, stored as P[q=a][kv] (bf16) ----
        #pragma unroll
        for (int T = 0; T < 4; ++T) {
            unsigned w0 = (unsigned)f2bf(p[T][0]) | ((unsigned)f2bf(p[T][1]) << 16);
            unsigned w1 = (unsigned)f2bf(p[T][2]) | ((unsigned)f2bf(p[T][3]) << 16);
            unsigned* dst = reinterpret_cast<unsigned*>(&Pl[w][a][16 * T + 4 * g]);
            dst[0] = w0;
            dst[1] = w1;
        }

        // ---- PV: O^T tiles (d blocks of 16) x 2 K-chunks of 32 kv ----
        #pragma unroll
        for (int c = 0; c < 2; ++c) {
            bf16x8 pf = *reinterpret_cast<const bf16x8*>(&Pl[w][a][32 * c + 8 * g]);
            #pragma unroll
            for (int t = 0; t < 4; ++t) {
                const unsigned short* vp =
                    vhead + (size_t)(16 * t + a) * S_LEN + kt + 32 * c + 8 * g;
                bf16x8 vf = *reinterpret_cast<const bf16x8*>(vp);
                oacc[t] = __builtin_amdgcn_mfma_f32_16x16x32_bf16(vf, pf, oacc[t], 0, 0, 0);
            }
        }
    }

    // ---- epilogue: O[q][d] = O^T/l ----
    const float inv = 1.f / lrun;
    const int b = bh >> 4;
    const int h = bh & (NHEADS - 1);
    #pragma unroll
    for (int t = 0; t < 4; ++t) {
        float4 v;
        v.x = oacc[t][0] * inv;
        v.y = oacc[t][1] * inv;
        v.z = oacc[t][2] * inv;
        v.w = oacc[t][3] * inv;
        float* dst = o + ((size_t)(b * S_LEN + q0 + a)) * DMODEL + h * DK + 16 * t + 4 * g;
        *reinterpret_cast<float4*>(dst) = v;
    }
}

// ---------------------------------------------------------------------------
extern "C" void kernel_launch(void* const* d_in, const int* in_sizes, int n_in,
                              void* d_out, int out_size, void* d_ws, size_t ws_size,
                              hipStream_t stream)
{
    const float* Q  = (const float*)d_in[0];
    const float* K  = (const float*)d_in[1];
    const float* V  = (const float*)d_in[2];
    const float* Wq = (const float*)d_in[3];
    const float* bq = (const float*)d_in[4];
    const float* Wk = (const float*)d_in[5];
    const float* bk = (const float*)d_in[6];
    const float* Wv = (const float*)d_in[7];
    const float* bv = (const float*)d_in[8];
    const float* Wo = (const float*)d_in[9];
    const float* bo = (const float*)d_in[10];
    float* out = (float*)d_out;

    const size_t NELEM = (size_t)2 * NHEADS * S_LEN * DK;  // 4 Mi elements
    unsigned short* qb  = (unsigned short*)d_ws;
    unsigned short* kb  = qb + NELEM;
    unsigned short* vtb = kb + NELEM;
    float*          ob  = (float*)(vtb + NELEM);           // 16 MB fp32

    const int M = 2 * S_LEN;   // 4096
    const int N = DMODEL;      // 1024
    const int Kd = DMODEL;     // 1024

    dim3 gemm_grid(M / 64, N / 64);
    dim3 gemm_blk(256);

    gemm_bias_kernel<<<gemm_grid, gemm_blk, 0, stream>>>(Q, Wq, bq, qb,  M, N, Kd, 0);
    gemm_bias_kernel<<<gemm_grid, gemm_blk, 0, stream>>>(K, Wk, bk, kb,  M, N, Kd, 1);
    gemm_bias_kernel<<<gemm_grid, gemm_blk, 0, stream>>>(V, Wv, bv, vtb, M, N, Kd, 2);

    attn_mfma_kernel<<<dim3(S_LEN / 64, 2 * NHEADS), 256, 0, stream>>>(qb, kb, vtb, ob);

    gemm_bias_kernel<<<gemm_grid, gemm_blk, 0, stream>>>(ob, Wo, bo, out, M, N, Kd, 3);
}

// Round 7
// 311.370 us; speedup vs baseline: 8.2334x; 2.3972x over previous
//
#include <hip/hip_runtime.h>
#include <math.h>

#define S_LEN 2048
#define DMODEL 1024
#define NHEADS 16
#define DK 64

typedef __attribute__((ext_vector_type(8))) _Float16 f16x8;
typedef __attribute__((ext_vector_type(4))) float f32x4;

static __device__ __forceinline__ unsigned short f2h(float f) {
    _Float16 h = (_Float16)f;
    return __builtin_bit_cast(unsigned short, h);
}

static __device__ __forceinline__ void gload16(const void* g, void* l) {
    __builtin_amdgcn_global_load_lds(
        (const __attribute__((address_space(1))) void*)g,
        (__attribute__((address_space(3))) void*)l, 16, 0, 0);
}

// ---------------------------------------------------------------------------
// fp32 -> fp16 elementwise convert for Q, K, V inputs (z selects tensor).
// ---------------------------------------------------------------------------
__global__ __launch_bounds__(256)
void cvt_f16_kernel(const float* __restrict__ s0, const float* __restrict__ s1,
                    const float* __restrict__ s2, unsigned short* __restrict__ d)
{
    const int z = blockIdx.y;
    const float* src = z == 0 ? s0 : (z == 1 ? s1 : s2);
    unsigned short* dst = d + (size_t)z * 4194304;
    const int i = (blockIdx.x * 256 + threadIdx.x) * 8;
    float4 a = *reinterpret_cast<const float4*>(src + i);
    float4 b = *reinterpret_cast<const float4*>(src + i + 4);
    uint4 o;
    o.x = (unsigned)f2h(a.x) | ((unsigned)f2h(a.y) << 16);
    o.y = (unsigned)f2h(a.z) | ((unsigned)f2h(a.w) << 16);
    o.z = (unsigned)f2h(b.x) | ((unsigned)f2h(b.y) << 16);
    o.w = (unsigned)f2h(b.z) | ((unsigned)f2h(b.w) << 16);
    *reinterpret_cast<uint4*>(dst + i) = o;
}

// ---------------------------------------------------------------------------
// W [1024][1024] fp32 -> Wt [n][k] fp16 (transposed), LDS-tiled 64x64.
// z selects Wq/Wk/Wv/Wo.
// ---------------------------------------------------------------------------
__global__ __launch_bounds__(256)
void wprep_kernel(const float* __restrict__ w0, const float* __restrict__ w1,
                  const float* __restrict__ w2, const float* __restrict__ w3,
                  unsigned short* __restrict__ wt)
{
    __shared__ float tile[64][65];
    const int z = blockIdx.z;
    const float* W = z == 0 ? w0 : (z == 1 ? w1 : (z == 2 ? w2 : w3));
    unsigned short* Wt = wt + (size_t)z * 1048576;
    const int k0 = blockIdx.x * 64, n0 = blockIdx.y * 64;
    const int t = threadIdx.x;
    #pragma unroll
    for (int i = 0; i < 4; ++i) {
        int idx = i * 256 + t;
        int r = idx >> 4, c4 = (idx & 15) * 4;
        float4 v = *reinterpret_cast<const float4*>(W + (size_t)(k0 + r) * 1024 + n0 + c4);
        tile[r][c4 + 0] = v.x; tile[r][c4 + 1] = v.y;
        tile[r][c4 + 2] = v.z; tile[r][c4 + 3] = v.w;
    }
    __syncthreads();
    #pragma unroll
    for (int i = 0; i < 4; ++i) {
        int idx = i * 256 + t;
        int nr = idx >> 4, kc4 = (idx & 15) * 4;
        ushort4 h;
        h.x = f2h(tile[kc4 + 0][nr]); h.y = f2h(tile[kc4 + 1][nr]);
        h.z = f2h(tile[kc4 + 2][nr]); h.w = f2h(tile[kc4 + 3][nr]);
        *reinterpret_cast<ushort4*>(Wt + (size_t)(n0 + nr) * 1024 + k0 + kc4) = h;
    }
}

// ---------------------------------------------------------------------------
// MFMA fp16 GEMM: C[M=4096 slab][N=1024] = A[m][1024] @ Wt[n][1024]^T + bias
// Block 256 thr / 4 waves (2x2), tile 128x64, BK=64, global_load_lds staging.
// mode 0: q  -> fp16 [bh][s][dk], scaled 0.125
// mode 1: k  -> fp16 [bh][s][dk]
// mode 2: v  -> fp16 [bh][dk][s]  (transposed)
// mode 3: fp32 row-major out
// Projections launch with grid.z = 3 (mode = z); final GEMM mode_base = 3.
// ---------------------------------------------------------------------------
__global__ __launch_bounds__(256)
void gemm_mfma_kernel(const unsigned short* __restrict__ xh_base,
                      const unsigned short* __restrict__ wt_base,
                      const float* __restrict__ b0, const float* __restrict__ b1,
                      const float* __restrict__ b2,
                      void* __restrict__ dst_base, int mode_base)
{
    __shared__ short Als[128 * 64];
    __shared__ short Bls[64 * 64];

    const int z = blockIdx.z;
    const unsigned short* Ag = xh_base + (size_t)z * 4194304;
    const unsigned short* Bg = wt_base + (size_t)z * 1048576;
    const float* bias = z == 0 ? b0 : (z == 1 ? b1 : b2);
    const int mode = mode_base < 0 ? z : mode_base;

    const int tid = threadIdx.x;
    const int w = tid >> 6, l = tid & 63, a = l & 15, g = l >> 4;
    const int wm = w >> 1, wn = w & 1;
    const int bm = blockIdx.x * 128, bn = blockIdx.y * 64;

    f32x4 acc[4][2] = {};

    for (int k0 = 0; k0 < 1024; k0 += 64) {
        #pragma unroll
        for (int r2 = 0; r2 < 4; ++r2) {
            int idx = r2 * 256 + tid;
            gload16(Ag + (size_t)(bm + (idx >> 3)) * 1024 + k0 + (idx & 7) * 8,
                    (char*)Als + (size_t)(r2 * 256 + w * 64) * 16);
        }
        #pragma unroll
        for (int r2 = 0; r2 < 2; ++r2) {
            int idx = r2 * 256 + tid;
            gload16(Bg + (size_t)(bn + (idx >> 3)) * 1024 + k0 + (idx & 7) * 8,
                    (char*)Bls + (size_t)(r2 * 256 + w * 64) * 16);
        }
        __syncthreads();
        #pragma unroll
        for (int kc = 0; kc < 2; ++kc) {
            f16x8 af[4], bf[2];
            #pragma unroll
            for (int mi = 0; mi < 4; ++mi)
                af[mi] = *reinterpret_cast<const f16x8*>(
                    &Als[(wm * 64 + 16 * mi + a) * 64 + kc * 32 + g * 8]);
            #pragma unroll
            for (int ni = 0; ni < 2; ++ni)
                bf[ni] = *reinterpret_cast<const f16x8*>(
                    &Bls[(wn * 32 + 16 * ni + a) * 64 + kc * 32 + g * 8]);
            #pragma unroll
            for (int mi = 0; mi < 4; ++mi)
                #pragma unroll
                for (int ni = 0; ni < 2; ++ni)
                    acc[mi][ni] = __builtin_amdgcn_mfma_f32_16x16x32_f16(
                        af[mi], bf[ni], acc[mi][ni], 0, 0, 0);
        }
        __syncthreads();
    }

    void* mydst = (mode == 3) ? dst_base
                 : (void*)((unsigned short*)dst_base + (size_t)z * 4194304);

    #pragma unroll
    for (int ni = 0; ni < 2; ++ni) {
        const int n = bn + wn * 32 + 16 * ni + a;
        const float bv = bias[n];
        #pragma unroll
        for (int mi = 0; mi < 4; ++mi) {
            const int mbase = bm + wm * 64 + 16 * mi + g * 4;
            if (mode == 3) {
                float* o = (float*)mydst;
                #pragma unroll
                for (int r = 0; r < 4; ++r)
                    o[(size_t)(mbase + r) * 1024 + n] = acc[mi][ni][r] + bv;
            } else if (mode == 2) {
                unsigned short* o = (unsigned short*)mydst;
                const int b = mbase >> 11, s = mbase & (S_LEN - 1);
                const int h = n >> 6, d = n & (DK - 1);
                ushort4 st;
                st.x = f2h(acc[mi][ni][0] + bv);
                st.y = f2h(acc[mi][ni][1] + bv);
                st.z = f2h(acc[mi][ni][2] + bv);
                st.w = f2h(acc[mi][ni][3] + bv);
                *reinterpret_cast<ushort4*>(
                    o + ((size_t)((b * NHEADS + h) * DK + d)) * S_LEN + s) = st;
            } else {
                unsigned short* o = (unsigned short*)mydst;
                const float sc = (mode == 0) ? 0.125f : 1.0f;
                #pragma unroll
                for (int r = 0; r < 4; ++r) {
                    const int m = mbase + r;
                    const int b = m >> 11, s = m & (S_LEN - 1);
                    const int h = n >> 6, d = n & (DK - 1);
                    o[((size_t)((b * NHEADS + h) * S_LEN + s)) * DK + d] =
                        f2h((acc[mi][ni][r] + bv) * sc);
                }
            }
        }
    }
}

// ---------------------------------------------------------------------------
// MFMA flash attention, fp16 operands, fp32 softmax/accum.
//   qb: fp16 [bh][s][64] (pre-scaled 1/8),  kb: fp16 [bh][s][64]
//   vt: fp16 [bh][64][s] (V transposed),    ob: fp16 [b*s][1024]
// ---------------------------------------------------------------------------
__global__ __launch_bounds__(256)
void attn_mfma_kernel(const unsigned short* __restrict__ qb,
                      const unsigned short* __restrict__ kb,
                      const unsigned short* __restrict__ vt,
                      unsigned short* __restrict__ ob)
{
    __shared__ unsigned short Pl[4][16][72];

    const int tid = threadIdx.x;
    const int w = tid >> 6;
    const int l = tid & 63;
    const int a = l & 15;
    const int g = l >> 4;
    const int bh = blockIdx.y;
    const int q0 = blockIdx.x * 64 + w * 16;

    const unsigned short* qhead = qb + (size_t)bh * S_LEN * DK;
    const unsigned short* khead = kb + (size_t)bh * S_LEN * DK;
    const unsigned short* vhead = vt + (size_t)bh * DK * S_LEN;

    f16x8 qf0 = *reinterpret_cast<const f16x8*>(qhead + (size_t)(q0 + a) * DK + 8 * g);
    f16x8 qf1 = *reinterpret_cast<const f16x8*>(qhead + (size_t)(q0 + a) * DK + 32 + 8 * g);

    f32x4 oacc[4];
    #pragma unroll
    for (int t = 0; t < 4; ++t) oacc[t] = (f32x4){0.f, 0.f, 0.f, 0.f};
    float mrun = -INFINITY;
    float lrun = 0.f;
    const float L2E = 1.44269504f;

    for (int kt = 0; kt < S_LEN; kt += 64) {
        f32x4 sacc[4];
        #pragma unroll
        for (int T = 0; T < 4; ++T) sacc[T] = (f32x4){0.f, 0.f, 0.f, 0.f};
        #pragma unroll
        for (int T = 0; T < 4; ++T) {
            const unsigned short* kp = khead + (size_t)(kt + 16 * T + a) * DK + 8 * g;
            f16x8 k0 = *reinterpret_cast<const f16x8*>(kp);
            f16x8 k1 = *reinterpret_cast<const f16x8*>(kp + 32);
            sacc[T] = __builtin_amdgcn_mfma_f32_16x16x32_f16(k0, qf0, sacc[T], 0, 0, 0);
            sacc[T] = __builtin_amdgcn_mfma_f32_16x16x32_f16(k1, qf1, sacc[T], 0, 0, 0);
        }

        float vmax = -INFINITY;
        #pragma unroll
        for (int T = 0; T < 4; ++T)
            #pragma unroll
            for (int r = 0; r < 4; ++r) vmax = fmaxf(vmax, sacc[T][r]);
        vmax = fmaxf(vmax, __shfl_xor(vmax, 16));
        vmax = fmaxf(vmax, __shfl_xor(vmax, 32));
        const float mnew = fmaxf(mrun, vmax);
        const float corr = exp2f((mrun - mnew) * L2E);

        float p[4][4];
        float ts = 0.f;
        #pragma unroll
        for (int T = 0; T < 4; ++T)
            #pragma unroll
            for (int r = 0; r < 4; ++r) {
                float e = exp2f((sacc[T][r] - mnew) * L2E);
                p[T][r] = e;
                ts += e;
            }
        ts += __shfl_xor(ts, 16);
        ts += __shfl_xor(ts, 32);
        lrun = lrun * corr + ts;
        mrun = mnew;

        #pragma unroll
        for (int t = 0; t < 4; ++t) {
            oacc[t][0] *= corr; oacc[t][1] *= corr;
            oacc[t][2] *= corr; oacc[t][3] *= corr;
        }

        #pragma unroll
        for (int T = 0; T < 4; ++T) {
            unsigned w0 = (unsigned)f2h(p[T][0]) | ((unsigned)f2h(p[T][1]) << 16);
            unsigned w1 = (unsigned)f2h(p[T][2]) | ((unsigned)f2h(p[T][3]) << 16);
            unsigned* dst = reinterpret_cast<unsigned*>(&Pl[w][a][16 * T + 4 * g]);
            dst[0] = w0;
            dst[1] = w1;
        }

        #pragma unroll
        for (int c = 0; c < 2; ++c) {
            f16x8 pf = *reinterpret_cast<const f16x8*>(&Pl[w][a][32 * c + 8 * g]);
            #pragma unroll
            for (int t = 0; t < 4; ++t) {
                const unsigned short* vp =
                    vhead + (size_t)(16 * t + a) * S_LEN + kt + 32 * c + 8 * g;
                f16x8 vf = *reinterpret_cast<const f16x8*>(vp);
                oacc[t] = __builtin_amdgcn_mfma_f32_16x16x32_f16(vf, pf, oacc[t], 0, 0, 0);
            }
        }
    }

    const float inv = 1.f / lrun;
    const int b = bh >> 4;
    const int h = bh & (NHEADS - 1);
    #pragma unroll
    for (int t = 0; t < 4; ++t) {
        ushort4 st;
        st.x = f2h(oacc[t][0] * inv);
        st.y = f2h(oacc[t][1] * inv);
        st.z = f2h(oacc[t][2] * inv);
        st.w = f2h(oacc[t][3] * inv);
        unsigned short* dst =
            ob + ((size_t)(b * S_LEN + q0 + a)) * DMODEL + h * DK + 16 * t + 4 * g;
        *reinterpret_cast<ushort4*>(dst) = st;
    }
}

// ---------------------------------------------------------------------------
extern "C" void kernel_launch(void* const* d_in, const int* in_sizes, int n_in,
                              void* d_out, int out_size, void* d_ws, size_t ws_size,
                              hipStream_t stream)
{
    const float* Q  = (const float*)d_in[0];
    const float* K  = (const float*)d_in[1];
    const float* V  = (const float*)d_in[2];
    const float* Wq = (const float*)d_in[3];
    const float* bq = (const float*)d_in[4];
    const float* Wk = (const float*)d_in[5];
    const float* bk = (const float*)d_in[6];
    const float* Wv = (const float*)d_in[7];
    const float* bv = (const float*)d_in[8];
    const float* Wo = (const float*)d_in[9];
    const float* bo = (const float*)d_in[10];
    float* out = (float*)d_out;

    // ws layout (fp16 elems): xh[3*4M] wt[4*1M] qb[4M] kb[4M] vtb[4M] ob[4M]
    unsigned short* xh  = (unsigned short*)d_ws;
    unsigned short* wt  = xh + (size_t)3 * 4194304;
    unsigned short* qb  = wt + (size_t)4 * 1048576;
    unsigned short* kb  = qb + 4194304;
    unsigned short* vtb = kb + 4194304;
    unsigned short* obh = vtb + 4194304;

    cvt_f16_kernel<<<dim3(2048, 3), 256, 0, stream>>>(Q, K, V, xh);
    wprep_kernel<<<dim3(16, 16, 4), 256, 0, stream>>>(Wq, Wk, Wv, Wo, wt);

    // q/k/v projections (z-fused): modes 0,1,2
    gemm_mfma_kernel<<<dim3(32, 16, 3), 256, 0, stream>>>(
        xh, wt, bq, bk, bv, qb, -1);

    attn_mfma_kernel<<<dim3(S_LEN / 64, 2 * NHEADS), 256, 0, stream>>>(qb, kb, vtb, obh);

    // output projection: mode 3
    gemm_mfma_kernel<<<dim3(32, 16, 1), 256, 0, stream>>>(
        obh, wt + (size_t)3 * 1048576, bo, bo, bo, out, 3);
}

// Round 8
// 174.262 us; speedup vs baseline: 14.7114x; 1.7868x over previous
//
#include <hip/hip_runtime.h>
#include <math.h>

#define S_LEN 2048
#define DMODEL 1024
#define NHEADS 16
#define DK 64

typedef __attribute__((ext_vector_type(8))) _Float16 f16x8;
typedef __attribute__((ext_vector_type(4))) float f32x4;

static __device__ __forceinline__ unsigned short f2h(float f) {
    _Float16 h = (_Float16)f;
    return __builtin_bit_cast(unsigned short, h);
}

static __device__ __forceinline__ void gload16(const void* g, void* l) {
    __builtin_amdgcn_global_load_lds(
        (const __attribute__((address_space(1))) void*)g,
        (__attribute__((address_space(3))) void*)l, 16, 0, 0);
}

// ---------------------------------------------------------------------------
// fp32 -> fp16 elementwise convert for Q, K, V inputs (z selects tensor).
// ---------------------------------------------------------------------------
__global__ __launch_bounds__(256)
void cvt_f16_kernel(const float* __restrict__ s0, const float* __restrict__ s1,
                    const float* __restrict__ s2, unsigned short* __restrict__ d)
{
    const int z = blockIdx.y;
    const float* src = z == 0 ? s0 : (z == 1 ? s1 : s2);
    unsigned short* dst = d + (size_t)z * 4194304;
    const int i = (blockIdx.x * 256 + threadIdx.x) * 8;
    float4 a = *reinterpret_cast<const float4*>(src + i);
    float4 b = *reinterpret_cast<const float4*>(src + i + 4);
    uint4 o;
    o.x = (unsigned)f2h(a.x) | ((unsigned)f2h(a.y) << 16);
    o.y = (unsigned)f2h(a.z) | ((unsigned)f2h(a.w) << 16);
    o.z = (unsigned)f2h(b.x) | ((unsigned)f2h(b.y) << 16);
    o.w = (unsigned)f2h(b.z) | ((unsigned)f2h(b.w) << 16);
    *reinterpret_cast<uint4*>(dst + i) = o;
}

// ---------------------------------------------------------------------------
// W [1024][1024] fp32 -> Wt [n][k] fp16 (transposed), LDS-tiled 64x64.
// z selects Wq/Wk/Wv/Wo.
// ---------------------------------------------------------------------------
__global__ __launch_bounds__(256)
void wprep_kernel(const float* __restrict__ w0, const float* __restrict__ w1,
                  const float* __restrict__ w2, const float* __restrict__ w3,
                  unsigned short* __restrict__ wt)
{
    __shared__ float tile[64][65];
    const int z = blockIdx.z;
    const float* W = z == 0 ? w0 : (z == 1 ? w1 : (z == 2 ? w2 : w3));
    unsigned short* Wt = wt + (size_t)z * 1048576;
    const int k0 = blockIdx.x * 64, n0 = blockIdx.y * 64;
    const int t = threadIdx.x;
    #pragma unroll
    for (int i = 0; i < 4; ++i) {
        int idx = i * 256 + t;
        int r = idx >> 4, c4 = (idx & 15) * 4;
        float4 v = *reinterpret_cast<const float4*>(W + (size_t)(k0 + r) * 1024 + n0 + c4);
        tile[r][c4 + 0] = v.x; tile[r][c4 + 1] = v.y;
        tile[r][c4 + 2] = v.z; tile[r][c4 + 3] = v.w;
    }
    __syncthreads();
    #pragma unroll
    for (int i = 0; i < 4; ++i) {
        int idx = i * 256 + t;
        int nr = idx >> 4, kc4 = (idx & 15) * 4;
        ushort4 h;
        h.x = f2h(tile[kc4 + 0][nr]); h.y = f2h(tile[kc4 + 1][nr]);
        h.z = f2h(tile[kc4 + 2][nr]); h.w = f2h(tile[kc4 + 3][nr]);
        *reinterpret_cast<ushort4*>(Wt + (size_t)(n0 + nr) * 1024 + k0 + kc4) = h;
    }
}

// ---------------------------------------------------------------------------
// MFMA fp16 GEMM: C[M=4096 slab][N=1024] = A[m][1024] @ Wt[n][1024]^T + bias
// Block 256 thr / 4 waves (2x2), tile 128x64, BK=64, global_load_lds staging.
// mode 0: q  -> fp16 [bh][s][dk], scaled 0.125
// mode 1: k  -> fp16 [bh][s][dk]
// mode 2: v  -> fp16 [bh][dk][s]  (transposed)
// mode 3: fp32 row-major out
// ---------------------------------------------------------------------------
__global__ __launch_bounds__(256)
void gemm_mfma_kernel(const unsigned short* __restrict__ xh_base,
                      const unsigned short* __restrict__ wt_base,
                      const float* __restrict__ b0, const float* __restrict__ b1,
                      const float* __restrict__ b2,
                      void* __restrict__ dst_base, int mode_base)
{
    __shared__ short Als[128 * 64];
    __shared__ short Bls[64 * 64];

    const int z = blockIdx.z;
    const unsigned short* Ag = xh_base + (size_t)z * 4194304;
    const unsigned short* Bg = wt_base + (size_t)z * 1048576;
    const float* bias = z == 0 ? b0 : (z == 1 ? b1 : b2);
    const int mode = mode_base < 0 ? z : mode_base;

    const int tid = threadIdx.x;
    const int w = tid >> 6, l = tid & 63, a = l & 15, g = l >> 4;
    const int wm = w >> 1, wn = w & 1;
    const int bm = blockIdx.x * 128, bn = blockIdx.y * 64;

    f32x4 acc[4][2] = {};

    for (int k0 = 0; k0 < 1024; k0 += 64) {
        #pragma unroll
        for (int r2 = 0; r2 < 4; ++r2) {
            int idx = r2 * 256 + tid;
            gload16(Ag + (size_t)(bm + (idx >> 3)) * 1024 + k0 + (idx & 7) * 8,
                    (char*)Als + (size_t)(r2 * 256 + w * 64) * 16);
        }
        #pragma unroll
        for (int r2 = 0; r2 < 2; ++r2) {
            int idx = r2 * 256 + tid;
            gload16(Bg + (size_t)(bn + (idx >> 3)) * 1024 + k0 + (idx & 7) * 8,
                    (char*)Bls + (size_t)(r2 * 256 + w * 64) * 16);
        }
        __syncthreads();
        #pragma unroll
        for (int kc = 0; kc < 2; ++kc) {
            f16x8 af[4], bf[2];
            #pragma unroll
            for (int mi = 0; mi < 4; ++mi)
                af[mi] = *reinterpret_cast<const f16x8*>(
                    &Als[(wm * 64 + 16 * mi + a) * 64 + kc * 32 + g * 8]);
            #pragma unroll
            for (int ni = 0; ni < 2; ++ni)
                bf[ni] = *reinterpret_cast<const f16x8*>(
                    &Bls[(wn * 32 + 16 * ni + a) * 64 + kc * 32 + g * 8]);
            #pragma unroll
            for (int mi = 0; mi < 4; ++mi)
                #pragma unroll
                for (int ni = 0; ni < 2; ++ni)
                    acc[mi][ni] = __builtin_amdgcn_mfma_f32_16x16x32_f16(
                        af[mi], bf[ni], acc[mi][ni], 0, 0, 0);
        }
        __syncthreads();
    }

    void* mydst = (mode == 3) ? dst_base
                 : (void*)((unsigned short*)dst_base + (size_t)z * 4194304);

    #pragma unroll
    for (int ni = 0; ni < 2; ++ni) {
        const int n = bn + wn * 32 + 16 * ni + a;
        const float bv = bias[n];
        #pragma unroll
        for (int mi = 0; mi < 4; ++mi) {
            const int mbase = bm + wm * 64 + 16 * mi + g * 4;
            if (mode == 3) {
                float* o = (float*)mydst;
                #pragma unroll
                for (int r = 0; r < 4; ++r)
                    o[(size_t)(mbase + r) * 1024 + n] = acc[mi][ni][r] + bv;
            } else if (mode == 2) {
                unsigned short* o = (unsigned short*)mydst;
                const int b = mbase >> 11, s = mbase & (S_LEN - 1);
                const int h = n >> 6, d = n & (DK - 1);
                ushort4 st;
                st.x = f2h(acc[mi][ni][0] + bv);
                st.y = f2h(acc[mi][ni][1] + bv);
                st.z = f2h(acc[mi][ni][2] + bv);
                st.w = f2h(acc[mi][ni][3] + bv);
                *reinterpret_cast<ushort4*>(
                    o + ((size_t)((b * NHEADS + h) * DK + d)) * S_LEN + s) = st;
            } else {
                unsigned short* o = (unsigned short*)mydst;
                const float sc = (mode == 0) ? 0.125f : 1.0f;
                #pragma unroll
                for (int r = 0; r < 4; ++r) {
                    const int m = mbase + r;
                    const int b = m >> 11, s = m & (S_LEN - 1);
                    const int h = n >> 6, d = n & (DK - 1);
                    o[((size_t)((b * NHEADS + h) * S_LEN + s)) * DK + d] =
                        f2h((acc[mi][ni][r] + bv) * sc);
                }
            }
        }
    }
}

// ---------------------------------------------------------------------------
// MFMA flash attention, v2: LDS-staged K/V (double-buffered, XOR-swizzled),
// 4 waves/block, each wave owns 32 q rows (2 groups of 16), KV tile = 64.
//   qb: fp16 [bh][s][64] (pre-scaled 1/8),  kb: fp16 [bh][s][64]
//   vt: fp16 [bh][64][s] (V transposed),    ob: fp16 [b*s][1024]
// Swizzle: LDS tile rows are 128 B; logical (row, colbyte) lives at LDS byte
// row*128 + (colbyte ^ ((row&7)<<4)). global_load_lds writes linearly, so the
// GLOBAL source address is pre-swizzled (rule: both-sides-or-neither).
// ---------------------------------------------------------------------------
__global__ __launch_bounds__(256)
void attn_mfma_kernel(const unsigned short* __restrict__ qb,
                      const unsigned short* __restrict__ kb,
                      const unsigned short* __restrict__ vt,
                      unsigned short* __restrict__ ob)
{
    __shared__ char Kls[2][8192];
    __shared__ char Vls[2][8192];
    __shared__ unsigned short Pl[4][32][72];

    const int tid = threadIdx.x;
    const int w = tid >> 6;
    const int l = tid & 63;
    const int a = l & 15;
    const int g = l >> 4;
    const int bh = blockIdx.y;
    const int q0 = blockIdx.x * 128 + w * 32;

    const unsigned short* qhead = qb + (size_t)bh * S_LEN * DK;
    const char* khead = (const char*)(kb + (size_t)bh * S_LEN * DK);
    const char* vhead = (const char*)(vt + (size_t)bh * DK * S_LEN);

    // Q fragments: [q-group j][k-chunk c]
    f16x8 qf[2][2];
    #pragma unroll
    for (int j = 0; j < 2; ++j)
        #pragma unroll
        for (int c = 0; c < 2; ++c)
            qf[j][c] = *reinterpret_cast<const f16x8*>(
                qhead + (size_t)(q0 + 16 * j + a) * DK + 32 * c + 8 * g);

    f32x4 oacc[4][2] = {};
    float mrun[2] = {-INFINITY, -INFINITY};
    float lrun[2] = {0.f, 0.f};
    const float L2E = 1.44269504f;

    // staging geometry: 256 threads, 16 B each = one 32-row half-tile per issue
    const int srow = tid >> 3;            // 0..31
    const int scol = (tid & 7) << 4;      // byte col 0..112

    #define STAGE(kt2, buf)                                                     \
        do {                                                                    \
            _Pragma("unroll")                                                   \
            for (int r2 = 0; r2 < 2; ++r2) {                                    \
                const int row = r2 * 32 + srow;                                 \
                const int gc = scol ^ ((row & 7) << 4);                         \
                gload16(khead + (size_t)((kt2) + row) * 128 + gc,               \
                        &Kls[buf][(size_t)(r2 * 4096 + w * 1024)]);             \
                gload16(vhead + (size_t)row * 4096 + (size_t)(kt2) * 2 + gc,    \
                        &Vls[buf][(size_t)(r2 * 4096 + w * 1024)]);             \
            }                                                                   \
        } while (0)

    STAGE(0, 0);
    __syncthreads();

    for (int kt = 0; kt < S_LEN; kt += 64) {
        const int cur = (kt >> 6) & 1;
        if (kt + 64 < S_LEN) STAGE(kt + 64, cur ^ 1);

        // ---- QK^T: S^T[kv][q], 4 kv-subtiles x 2 q-groups x 2 k-chunks ----
        f32x4 sacc[4][2] = {};
        #pragma unroll
        for (int c = 0; c < 2; ++c) {
            f16x8 kf[4];
            #pragma unroll
            for (int T = 0; T < 4; ++T) {
                const int row = 16 * T + a;
                kf[T] = *reinterpret_cast<const f16x8*>(
                    &Kls[cur][row * 128 + ((64 * c + 16 * g) ^ ((row & 7) << 4))]);
            }
            #pragma unroll
            for (int T = 0; T < 4; ++T)
                #pragma unroll
                for (int j = 0; j < 2; ++j)
                    sacc[T][j] = __builtin_amdgcn_mfma_f32_16x16x32_f16(
                        kf[T], qf[j][c], sacc[T][j], 0, 0, 0);
        }

        // ---- online softmax per q-group ----
        float corr[2];
        #pragma unroll
        for (int j = 0; j < 2; ++j) {
            float vmax = -INFINITY;
            #pragma unroll
            for (int T = 0; T < 4; ++T)
                #pragma unroll
                for (int r = 0; r < 4; ++r) vmax = fmaxf(vmax, sacc[T][j][r]);
            vmax = fmaxf(vmax, __shfl_xor(vmax, 16));
            vmax = fmaxf(vmax, __shfl_xor(vmax, 32));
            const float mnew = fmaxf(mrun[j], vmax);
            corr[j] = exp2f((mrun[j] - mnew) * L2E);

            float p[4][4];
            float ts = 0.f;
            #pragma unroll
            for (int T = 0; T < 4; ++T)
                #pragma unroll
                for (int r = 0; r < 4; ++r) {
                    float e = exp2f((sacc[T][j][r] - mnew) * L2E);
                    p[T][r] = e;
                    ts += e;
                }
            ts += __shfl_xor(ts, 16);
            ts += __shfl_xor(ts, 32);
            lrun[j] = lrun[j] * corr[j] + ts;
            mrun[j] = mnew;

            #pragma unroll
            for (int T = 0; T < 4; ++T) {
                unsigned w0 = (unsigned)f2h(p[T][0]) | ((unsigned)f2h(p[T][1]) << 16);
                unsigned w1 = (unsigned)f2h(p[T][2]) | ((unsigned)f2h(p[T][3]) << 16);
                unsigned* dst = reinterpret_cast<unsigned*>(
                    &Pl[w][16 * j + a][16 * T + 4 * g]);
                dst[0] = w0;
                dst[1] = w1;
            }
        }

        #pragma unroll
        for (int t = 0; t < 4; ++t)
            #pragma unroll
            for (int j = 0; j < 2; ++j) {
                oacc[t][j][0] *= corr[j]; oacc[t][j][1] *= corr[j];
                oacc[t][j][2] *= corr[j]; oacc[t][j][3] *= corr[j];
            }

        // ---- PV: O^T[d][q], V from swizzled LDS, P from per-wave LDS ----
        #pragma unroll
        for (int c = 0; c < 2; ++c) {
            f16x8 vf[4];
            #pragma unroll
            for (int t = 0; t < 4; ++t) {
                const int row = 16 * t + a;
                vf[t] = *reinterpret_cast<const f16x8*>(
                    &Vls[cur][row * 128 + ((64 * c + 16 * g) ^ ((row & 7) << 4))]);
            }
            f16x8 pf[2];
            #pragma unroll
            for (int j = 0; j < 2; ++j)
                pf[j] = *reinterpret_cast<const f16x8*>(
                    &Pl[w][16 * j + a][32 * c + 8 * g]);
            #pragma unroll
            for (int t = 0; t < 4; ++t)
                #pragma unroll
                for (int j = 0; j < 2; ++j)
                    oacc[t][j] = __builtin_amdgcn_mfma_f32_16x16x32_f16(
                        vf[t], pf[j], oacc[t][j], 0, 0, 0);
        }
        __syncthreads();
    }
    #undef STAGE

    const int b = bh >> 4;
    const int h = bh & (NHEADS - 1);
    #pragma unroll
    for (int j = 0; j < 2; ++j) {
        const float inv = 1.f / lrun[j];
        unsigned short* dst0 =
            ob + (size_t)(b * S_LEN + q0 + 16 * j + a) * DMODEL + h * DK;
        #pragma unroll
        for (int t = 0; t < 4; ++t) {
            ushort4 st;
            st.x = f2h(oacc[t][j][0] * inv);
            st.y = f2h(oacc[t][j][1] * inv);
            st.z = f2h(oacc[t][j][2] * inv);
            st.w = f2h(oacc[t][j][3] * inv);
            *reinterpret_cast<ushort4*>(dst0 + 16 * t + 4 * g) = st;
        }
    }
}

// ---------------------------------------------------------------------------
extern "C" void kernel_launch(void* const* d_in, const int* in_sizes, int n_in,
                              void* d_out, int out_size, void* d_ws, size_t ws_size,
                              hipStream_t stream)
{
    const float* Q  = (const float*)d_in[0];
    const float* K  = (const float*)d_in[1];
    const float* V  = (const float*)d_in[2];
    const float* Wq = (const float*)d_in[3];
    const float* bq = (const float*)d_in[4];
    const float* Wk = (const float*)d_in[5];
    const float* bk = (const float*)d_in[6];
    const float* Wv = (const float*)d_in[7];
    const float* bv = (const float*)d_in[8];
    const float* Wo = (const float*)d_in[9];
    const float* bo = (const float*)d_in[10];
    float* out = (float*)d_out;

    // ws layout (fp16 elems): xh[3*4M] wt[4*1M] qb[4M] kb[4M] vtb[4M] ob[4M]
    unsigned short* xh  = (unsigned short*)d_ws;
    unsigned short* wt  = xh + (size_t)3 * 4194304;
    unsigned short* qb  = wt + (size_t)4 * 1048576;
    unsigned short* kb  = qb + 4194304;
    unsigned short* vtb = kb + 4194304;
    unsigned short* obh = vtb + 4194304;

    cvt_f16_kernel<<<dim3(2048, 3), 256, 0, stream>>>(Q, K, V, xh);
    wprep_kernel<<<dim3(16, 16, 4), 256, 0, stream>>>(Wq, Wk, Wv, Wo, wt);

    // q/k/v projections (z-fused): modes 0,1,2
    gemm_mfma_kernel<<<dim3(32, 16, 3), 256, 0, stream>>>(
        xh, wt, bq, bk, bv, qb, -1);

    attn_mfma_kernel<<<dim3(S_LEN / 128, 2 * NHEADS), 256, 0, stream>>>(qb, kb, vtb, obh);

    // output projection: mode 3
    gemm_mfma_kernel<<<dim3(32, 16, 1), 256, 0, stream>>>(
        obh, wt + (size_t)3 * 1048576, bo, bo, bo, out, 3);
}

// Round 11
// 151.221 us; speedup vs baseline: 16.9529x; 1.1524x over previous
//
#include <hip/hip_runtime.h>
#include <math.h>

#define S_LEN 2048
#define DMODEL 1024
#define NHEADS 16
#define DK 64

// q-projection scale: 1/sqrt(dk) * log2(e)  -> softmax works in exp2 domain
#define QSCALE 0.1803368801111244f

typedef __attribute__((ext_vector_type(8))) _Float16 f16x8;
typedef __attribute__((ext_vector_type(2))) __fp16 hf16x2;
typedef __attribute__((ext_vector_type(4))) float f32x4;

static __device__ __forceinline__ unsigned short f2h(float f) {
    _Float16 h = (_Float16)f;
    return __builtin_bit_cast(unsigned short, h);
}

static __device__ __forceinline__ unsigned pack2(float a, float b) {
    hf16x2 h = __builtin_amdgcn_cvt_pkrtz(a, b);
    return __builtin_bit_cast(unsigned, h);
}

static __device__ __forceinline__ void gload16(const void* g, void* l) {
    __builtin_amdgcn_global_load_lds(
        (const __attribute__((address_space(1))) void*)g,
        (__attribute__((address_space(3))) void*)l, 16, 0, 0);
}

// ---------------------------------------------------------------------------
// fp32 -> fp16 elementwise convert for Q, K, V inputs (z selects tensor).
// ---------------------------------------------------------------------------
__global__ __launch_bounds__(256)
void cvt_f16_kernel(const float* __restrict__ s0, const float* __restrict__ s1,
                    const float* __restrict__ s2, unsigned short* __restrict__ d)
{
    const int z = blockIdx.y;
    const float* src = z == 0 ? s0 : (z == 1 ? s1 : s2);
    unsigned short* dst = d + (size_t)z * 4194304;
    const int i = (blockIdx.x * 256 + threadIdx.x) * 8;
    float4 a = *reinterpret_cast<const float4*>(src + i);
    float4 b = *reinterpret_cast<const float4*>(src + i + 4);
    uint4 o;
    o.x = (unsigned)f2h(a.x) | ((unsigned)f2h(a.y) << 16);
    o.y = (unsigned)f2h(a.z) | ((unsigned)f2h(a.w) << 16);
    o.z = (unsigned)f2h(b.x) | ((unsigned)f2h(b.y) << 16);
    o.w = (unsigned)f2h(b.z) | ((unsigned)f2h(b.w) << 16);
    *reinterpret_cast<uint4*>(dst + i) = o;
}

// ---------------------------------------------------------------------------
// W [1024][1024] fp32 -> Wt [n][k] fp16 (transposed), LDS-tiled 64x64.
// ---------------------------------------------------------------------------
__global__ __launch_bounds__(256)
void wprep_kernel(const float* __restrict__ w0, const float* __restrict__ w1,
                  const float* __restrict__ w2, const float* __restrict__ w3,
                  unsigned short* __restrict__ wt)
{
    __shared__ float tile[64][65];
    const int z = blockIdx.z;
    const float* W = z == 0 ? w0 : (z == 1 ? w1 : (z == 2 ? w2 : w3));
    unsigned short* Wt = wt + (size_t)z * 1048576;
    const int k0 = blockIdx.x * 64, n0 = blockIdx.y * 64;
    const int t = threadIdx.x;
    #pragma unroll
    for (int i = 0; i < 4; ++i) {
        int idx = i * 256 + t;
        int r = idx >> 4, c4 = (idx & 15) * 4;
        float4 v = *reinterpret_cast<const float4*>(W + (size_t)(k0 + r) * 1024 + n0 + c4);
        tile[r][c4 + 0] = v.x; tile[r][c4 + 1] = v.y;
        tile[r][c4 + 2] = v.z; tile[r][c4 + 3] = v.w;
    }
    __syncthreads();
    #pragma unroll
    for (int i = 0; i < 4; ++i) {
        int idx = i * 256 + t;
        int nr = idx >> 4, kc4 = (idx & 15) * 4;
        ushort4 h;
        h.x = f2h(tile[kc4 + 0][nr]); h.y = f2h(tile[kc4 + 1][nr]);
        h.z = f2h(tile[kc4 + 2][nr]); h.w = f2h(tile[kc4 + 3][nr]);
        *reinterpret_cast<ushort4*>(Wt + (size_t)(n0 + nr) * 1024 + k0 + kc4) = h;
    }
}

// ---------------------------------------------------------------------------
// MFMA fp16 GEMM: C[M=4096 slab][N=1024] = A[m][1024] @ Wt[n][1024]^T + bias
// mode 0: q (scaled QSCALE) / 1: k / 2: v transposed / 3: fp32 row-major out
// ---------------------------------------------------------------------------
__global__ __launch_bounds__(256)
void gemm_mfma_kernel(const unsigned short* __restrict__ xh_base,
                      const unsigned short* __restrict__ wt_base,
                      const float* __restrict__ b0, const float* __restrict__ b1,
                      const float* __restrict__ b2,
                      void* __restrict__ dst_base, int mode_base)
{
    __shared__ short Als[128 * 64];
    __shared__ short Bls[64 * 64];

    const int z = blockIdx.z;
    const unsigned short* Ag = xh_base + (size_t)z * 4194304;
    const unsigned short* Bg = wt_base + (size_t)z * 1048576;
    const float* bias = z == 0 ? b0 : (z == 1 ? b1 : b2);
    const int mode = mode_base < 0 ? z : mode_base;

    const int tid = threadIdx.x;
    const int w = tid >> 6, l = tid & 63, a = l & 15, g = l >> 4;
    const int wm = w >> 1, wn = w & 1;
    const int bm = blockIdx.x * 128, bn = blockIdx.y * 64;

    f32x4 acc[4][2] = {};

    for (int k0 = 0; k0 < 1024; k0 += 64) {
        #pragma unroll
        for (int r2 = 0; r2 < 4; ++r2) {
            int idx = r2 * 256 + tid;
            gload16(Ag + (size_t)(bm + (idx >> 3)) * 1024 + k0 + (idx & 7) * 8,
                    (char*)Als + (size_t)(r2 * 256 + w * 64) * 16);
        }
        #pragma unroll
        for (int r2 = 0; r2 < 2; ++r2) {
            int idx = r2 * 256 + tid;
            gload16(Bg + (size_t)(bn + (idx >> 3)) * 1024 + k0 + (idx & 7) * 8,
                    (char*)Bls + (size_t)(r2 * 256 + w * 64) * 16);
        }
        __syncthreads();
        #pragma unroll
        for (int kc = 0; kc < 2; ++kc) {
            f16x8 af[4], bf[2];
            #pragma unroll
            for (int mi = 0; mi < 4; ++mi)
                af[mi] = *reinterpret_cast<const f16x8*>(
                    &Als[(wm * 64 + 16 * mi + a) * 64 + kc * 32 + g * 8]);
            #pragma unroll
            for (int ni = 0; ni < 2; ++ni)
                bf[ni] = *reinterpret_cast<const f16x8*>(
                    &Bls[(wn * 32 + 16 * ni + a) * 64 + kc * 32 + g * 8]);
            #pragma unroll
            for (int mi = 0; mi < 4; ++mi)
                #pragma unroll
                for (int ni = 0; ni < 2; ++ni)
                    acc[mi][ni] = __builtin_amdgcn_mfma_f32_16x16x32_f16(
                        af[mi], bf[ni], acc[mi][ni], 0, 0, 0);
        }
        __syncthreads();
    }

    void* mydst = (mode == 3) ? dst_base
                 : (void*)((unsigned short*)dst_base + (size_t)z * 4194304);

    #pragma unroll
    for (int ni = 0; ni < 2; ++ni) {
        const int n = bn + wn * 32 + 16 * ni + a;
        const float bv = bias[n];
        #pragma unroll
        for (int mi = 0; mi < 4; ++mi) {
            const int mbase = bm + wm * 64 + 16 * mi + g * 4;
            if (mode == 3) {
                float* o = (float*)mydst;
                #pragma unroll
                for (int r = 0; r < 4; ++r)
                    o[(size_t)(mbase + r) * 1024 + n] = acc[mi][ni][r] + bv;
            } else if (mode == 2) {
                unsigned short* o = (unsigned short*)mydst;
                const int b = mbase >> 11, s = mbase & (S_LEN - 1);
                const int h = n >> 6, d = n & (DK - 1);
                ushort4 st;
                st.x = f2h(acc[mi][ni][0] + bv);
                st.y = f2h(acc[mi][ni][1] + bv);
                st.z = f2h(acc[mi][ni][2] + bv);
                st.w = f2h(acc[mi][ni][3] + bv);
                *reinterpret_cast<ushort4*>(
                    o + ((size_t)((b * NHEADS + h) * DK + d)) * S_LEN + s) = st;
            } else {
                unsigned short* o = (unsigned short*)mydst;
                const float sc = (mode == 0) ? QSCALE : 1.0f;
                #pragma unroll
                for (int r = 0; r < 4; ++r) {
                    const int m = mbase + r;
                    const int b = m >> 11, s = m & (S_LEN - 1);
                    const int h = n >> 6, d = n & (DK - 1);
                    o[((size_t)((b * NHEADS + h) * S_LEN + s)) * DK + d] =
                        f2h((acc[mi][ni][r] + bv) * sc);
                }
            }
        }
    }
}

// ---------------------------------------------------------------------------
// MFMA flash attention v3: LDS-staged K/V (dbuf, XOR-swizzled), 4 waves,
// 32 q rows/wave; exp2-domain softmax, defer-max, cvt_pkrtz, setprio.
// ---------------------------------------------------------------------------
__global__ __launch_bounds__(256)
void attn_mfma_kernel(const unsigned short* __restrict__ qb,
                      const unsigned short* __restrict__ kb,
                      const unsigned short* __restrict__ vt,
                      unsigned short* __restrict__ ob)
{
    __shared__ char Kls[2][8192];
    __shared__ char Vls[2][8192];
    __shared__ unsigned short Pl[4][32][72];

    const int tid = threadIdx.x;
    const int w = tid >> 6;
    const int l = tid & 63;
    const int a = l & 15;
    const int g = l >> 4;
    const int bh = blockIdx.y;
    const int q0 = blockIdx.x * 128 + w * 32;

    const unsigned short* qhead = qb + (size_t)bh * S_LEN * DK;
    const char* khead = (const char*)(kb + (size_t)bh * S_LEN * DK);
    const char* vhead = (const char*)(vt + (size_t)bh * DK * S_LEN);

    // Q fragments (already scaled by 1/sqrt(dk)*log2e): [q-group j][k-chunk c]
    f16x8 qf[2][2];
    #pragma unroll
    for (int j = 0; j < 2; ++j)
        #pragma unroll
        for (int c = 0; c < 2; ++c)
            qf[j][c] = *reinterpret_cast<const f16x8*>(
                qhead + (size_t)(q0 + 16 * j + a) * DK + 32 * c + 8 * g);

    f32x4 oacc[4][2] = {};
    float mrun[2] = {-INFINITY, -INFINITY};
    float lrun[2] = {0.f, 0.f};

    const int srow = tid >> 3;            // 0..31
    const int scol = (tid & 7) << 4;      // byte col 0..112

    #define STAGE(kt2, buf)                                                     \
        do {                                                                    \
            _Pragma("unroll")                                                   \
            for (int r2 = 0; r2 < 2; ++r2) {                                    \
                const int row = r2 * 32 + srow;                                 \
                const int gc = scol ^ ((row & 7) << 4);                         \
                gload16(khead + (size_t)((kt2) + row) * 128 + gc,               \
                        &Kls[buf][(size_t)(r2 * 4096 + w * 1024)]);             \
                gload16(vhead + (size_t)row * 4096 + (size_t)(kt2) * 2 + gc,    \
                        &Vls[buf][(size_t)(r2 * 4096 + w * 1024)]);             \
            }                                                                   \
        } while (0)

    STAGE(0, 0);
    __syncthreads();

    for (int kt = 0; kt < S_LEN; kt += 64) {
        const int cur = (kt >> 6) & 1;
        if (kt + 64 < S_LEN) STAGE(kt + 64, cur ^ 1);

        // ---- K fragments, then one QK^T MFMA burst ----
        f16x8 kf[2][4];
        #pragma unroll
        for (int c = 0; c < 2; ++c)
            #pragma unroll
            for (int T = 0; T < 4; ++T) {
                const int row = 16 * T + a;
                kf[c][T] = *reinterpret_cast<const f16x8*>(
                    &Kls[cur][row * 128 + ((64 * c + 16 * g) ^ ((row & 7) << 4))]);
            }
        f32x4 sacc[4][2] = {};
        __builtin_amdgcn_s_setprio(1);
        #pragma unroll
        for (int c = 0; c < 2; ++c)
            #pragma unroll
            for (int T = 0; T < 4; ++T)
                #pragma unroll
                for (int j = 0; j < 2; ++j)
                    sacc[T][j] = __builtin_amdgcn_mfma_f32_16x16x32_f16(
                        kf[c][T], qf[j][c], sacc[T][j], 0, 0, 0);
        __builtin_amdgcn_s_setprio(0);

        // ---- V fragments early: LDS latency hides under softmax VALU ----
        f16x8 vf[2][4];
        #pragma unroll
        for (int c = 0; c < 2; ++c)
            #pragma unroll
            for (int t = 0; t < 4; ++t) {
                const int row = 16 * t + a;
                vf[c][t] = *reinterpret_cast<const f16x8*>(
                    &Vls[cur][row * 128 + ((64 * c + 16 * g) ^ ((row & 7) << 4))]);
            }

        // ---- online softmax per q-group (exp2 domain, defer-max) ----
        #pragma unroll
        for (int j = 0; j < 2; ++j) {
            float vmax = sacc[0][j][0];
            #pragma unroll
            for (int T = 0; T < 4; ++T)
                #pragma unroll
                for (int r = 0; r < 4; ++r)
                    if (T + r) vmax = fmaxf(vmax, sacc[T][j][r]);
            vmax = fmaxf(vmax, __shfl_xor(vmax, 16));
            vmax = fmaxf(vmax, __shfl_xor(vmax, 32));

            if (!__all(vmax <= mrun[j] + 8.f)) {
                const float mnew = fmaxf(mrun[j], vmax);
                const float corr = __builtin_amdgcn_exp2f(mrun[j] - mnew);
                lrun[j] *= corr;
                #pragma unroll
                for (int t = 0; t < 4; ++t) {
                    oacc[t][j][0] *= corr; oacc[t][j][1] *= corr;
                    oacc[t][j][2] *= corr; oacc[t][j][3] *= corr;
                }
                mrun[j] = mnew;
            }

            const float mj = mrun[j];
            float p[4][4];
            float ts = 0.f;
            #pragma unroll
            for (int T = 0; T < 4; ++T)
                #pragma unroll
                for (int r = 0; r < 4; ++r) {
                    float e = __builtin_amdgcn_exp2f(sacc[T][j][r] - mj);
                    p[T][r] = e;
                    ts += e;
                }
            ts += __shfl_xor(ts, 16);
            ts += __shfl_xor(ts, 32);
            lrun[j] += ts;

            #pragma unroll
            for (int T = 0; T < 4; ++T) {
                unsigned* dst = reinterpret_cast<unsigned*>(
                    &Pl[w][16 * j + a][16 * T + 4 * g]);
                dst[0] = pack2(p[T][0], p[T][1]);
                dst[1] = pack2(p[T][2], p[T][3]);
            }
        }

        // ---- PV: O^T[d][q] ----
        #pragma unroll
        for (int c = 0; c < 2; ++c) {
            f16x8 pf[2];
            #pragma unroll
            for (int j = 0; j < 2; ++j)
                pf[j] = *reinterpret_cast<const f16x8*>(
                    &Pl[w][16 * j + a][32 * c + 8 * g]);
            __builtin_amdgcn_s_setprio(1);
            #pragma unroll
            for (int t = 0; t < 4; ++t)
                #pragma unroll
                for (int j = 0; j < 2; ++j)
                    oacc[t][j] = __builtin_amdgcn_mfma_f32_16x16x32_f16(
                        vf[c][t], pf[j], oacc[t][j], 0, 0, 0);
            __builtin_amdgcn_s_setprio(0);
        }
        __syncthreads();
    }
    #undef STAGE

    const int b = bh >> 4;
    const int h = bh & (NHEADS - 1);
    #pragma unroll
    for (int j = 0; j < 2; ++j) {
        const float inv = 1.f / lrun[j];
        unsigned short* dst0 =
            ob + (size_t)(b * S_LEN + q0 + 16 * j + a) * DMODEL + h * DK;
        #pragma unroll
        for (int t = 0; t < 4; ++t) {
            ushort4 st;
            st.x = f2h(oacc[t][j][0] * inv);
            st.y = f2h(oacc[t][j][1] * inv);
            st.z = f2h(oacc[t][j][2] * inv);
            st.w = f2h(oacc[t][j][3] * inv);
            *reinterpret_cast<ushort4*>(dst0 + 16 * t + 4 * g) = st;
        }
    }
}

// ---------------------------------------------------------------------------
extern "C" void kernel_launch(void* const* d_in, const int* in_sizes, int n_in,
                              void* d_out, int out_size, void* d_ws, size_t ws_size,
                              hipStream_t stream)
{
    const float* Q  = (const float*)d_in[0];
    const float* K  = (const float*)d_in[1];
    const float* V  = (const float*)d_in[2];
    const float* Wq = (const float*)d_in[3];
    const float* bq = (const float*)d_in[4];
    const float* Wk = (const float*)d_in[5];
    const float* bk = (const float*)d_in[6];
    const float* Wv = (const float*)d_in[7];
    const float* bv = (const float*)d_in[8];
    const float* Wo = (const float*)d_in[9];
    const float* bo = (const float*)d_in[10];
    float* out = (float*)d_out;

    // ws layout (fp16 elems): xh[3*4M] wt[4*1M] qb[4M] kb[4M] vtb[4M] ob[4M]
    unsigned short* xh  = (unsigned short*)d_ws;
    unsigned short* wt  = xh + (size_t)3 * 4194304;
    unsigned short* qb  = wt + (size_t)4 * 1048576;
    unsigned short* kb  = qb + 4194304;
    unsigned short* vtb = kb + 4194304;
    unsigned short* obh = vtb + 4194304;

    cvt_f16_kernel<<<dim3(2048, 3), 256, 0, stream>>>(Q, K, V, xh);
    wprep_kernel<<<dim3(16, 16, 4), 256, 0, stream>>>(Wq, Wk, Wv, Wo, wt);

    gemm_mfma_kernel<<<dim3(32, 16, 3), 256, 0, stream>>>(
        xh, wt, bq, bk, bv, qb, -1);

    attn_mfma_kernel<<<dim3(S_LEN / 128, 2 * NHEADS), 256, 0, stream>>>(qb, kb, vtb, obh);

    gemm_mfma_kernel<<<dim3(32, 16, 1), 256, 0, stream>>>(
        obh, wt + (size_t)3 * 1048576, bo, bo, bo, out, 3);
}

// Round 12
// 137.150 us; speedup vs baseline: 18.6921x; 1.1026x over previous
//
#include <hip/hip_runtime.h>
#include <math.h>

#define S_LEN 2048
#define DMODEL 1024
#define NHEADS 16
#define DK 64

// q-projection scale: 1/sqrt(dk) * log2(e)  -> softmax works in exp2 domain
#define QSCALE 0.1803368801111244f

typedef __attribute__((ext_vector_type(8))) _Float16 f16x8;
typedef __attribute__((ext_vector_type(2))) __fp16 hf16x2;
typedef __attribute__((ext_vector_type(4))) float f32x4;

static __device__ __forceinline__ unsigned short f2h(float f) {
    _Float16 h = (_Float16)f;
    return __builtin_bit_cast(unsigned short, h);
}

static __device__ __forceinline__ unsigned pack2(float a, float b) {
    hf16x2 h = __builtin_amdgcn_cvt_pkrtz(a, b);
    return __builtin_bit_cast(unsigned, h);
}

static __device__ __forceinline__ void gload16(const void* g, void* l) {
    __builtin_amdgcn_global_load_lds(
        (const __attribute__((address_space(1))) void*)g,
        (__attribute__((address_space(3))) void*)l, 16, 0, 0);
}

// ---------------------------------------------------------------------------
// fp32 -> fp16 elementwise convert for Q, K, V inputs (z selects tensor).
// ---------------------------------------------------------------------------
__global__ __launch_bounds__(256)
void cvt_f16_kernel(const float* __restrict__ s0, const float* __restrict__ s1,
                    const float* __restrict__ s2, unsigned short* __restrict__ d)
{
    const int z = blockIdx.y;
    const float* src = z == 0 ? s0 : (z == 1 ? s1 : s2);
    unsigned short* dst = d + (size_t)z * 4194304;
    const int i = (blockIdx.x * 256 + threadIdx.x) * 8;
    float4 a = *reinterpret_cast<const float4*>(src + i);
    float4 b = *reinterpret_cast<const float4*>(src + i + 4);
    uint4 o;
    o.x = (unsigned)f2h(a.x) | ((unsigned)f2h(a.y) << 16);
    o.y = (unsigned)f2h(a.z) | ((unsigned)f2h(a.w) << 16);
    o.z = (unsigned)f2h(b.x) | ((unsigned)f2h(b.y) << 16);
    o.w = (unsigned)f2h(b.z) | ((unsigned)f2h(b.w) << 16);
    *reinterpret_cast<uint4*>(dst + i) = o;
}

// ---------------------------------------------------------------------------
// W [1024][1024] fp32 -> Wt [n][k] fp16 (transposed), LDS-tiled 64x64.
// ---------------------------------------------------------------------------
__global__ __launch_bounds__(256)
void wprep_kernel(const float* __restrict__ w0, const float* __restrict__ w1,
                  const float* __restrict__ w2, const float* __restrict__ w3,
                  unsigned short* __restrict__ wt)
{
    __shared__ float tile[64][65];
    const int z = blockIdx.z;
    const float* W = z == 0 ? w0 : (z == 1 ? w1 : (z == 2 ? w2 : w3));
    unsigned short* Wt = wt + (size_t)z * 1048576;
    const int k0 = blockIdx.x * 64, n0 = blockIdx.y * 64;
    const int t = threadIdx.x;
    #pragma unroll
    for (int i = 0; i < 4; ++i) {
        int idx = i * 256 + t;
        int r = idx >> 4, c4 = (idx & 15) * 4;
        float4 v = *reinterpret_cast<const float4*>(W + (size_t)(k0 + r) * 1024 + n0 + c4);
        tile[r][c4 + 0] = v.x; tile[r][c4 + 1] = v.y;
        tile[r][c4 + 2] = v.z; tile[r][c4 + 3] = v.w;
    }
    __syncthreads();
    #pragma unroll
    for (int i = 0; i < 4; ++i) {
        int idx = i * 256 + t;
        int nr = idx >> 4, kc4 = (idx & 15) * 4;
        ushort4 h;
        h.x = f2h(tile[kc4 + 0][nr]); h.y = f2h(tile[kc4 + 1][nr]);
        h.z = f2h(tile[kc4 + 2][nr]); h.w = f2h(tile[kc4 + 3][nr]);
        *reinterpret_cast<ushort4*>(Wt + (size_t)(n0 + nr) * 1024 + k0 + kc4) = h;
    }
}

// ---------------------------------------------------------------------------
// MFMA fp16 GEMM: C[M=4096 slab][N=1024] = A[m][1024] @ Wt[n][1024]^T + bias
// mode 0: q (scaled QSCALE) / 1: k / 2: v transposed / 3: fp32 row-major out
// ---------------------------------------------------------------------------
__global__ __launch_bounds__(256)
void gemm_mfma_kernel(const unsigned short* __restrict__ xh_base,
                      const unsigned short* __restrict__ wt_base,
                      const float* __restrict__ b0, const float* __restrict__ b1,
                      const float* __restrict__ b2,
                      void* __restrict__ dst_base, int mode_base)
{
    __shared__ short Als[128 * 64];
    __shared__ short Bls[64 * 64];

    const int z = blockIdx.z;
    const unsigned short* Ag = xh_base + (size_t)z * 4194304;
    const unsigned short* Bg = wt_base + (size_t)z * 1048576;
    const float* bias = z == 0 ? b0 : (z == 1 ? b1 : b2);
    const int mode = mode_base < 0 ? z : mode_base;

    const int tid = threadIdx.x;
    const int w = tid >> 6, l = tid & 63, a = l & 15, g = l >> 4;
    const int wm = w >> 1, wn = w & 1;
    const int bm = blockIdx.x * 128, bn = blockIdx.y * 64;

    f32x4 acc[4][2] = {};

    for (int k0 = 0; k0 < 1024; k0 += 64) {
        #pragma unroll
        for (int r2 = 0; r2 < 4; ++r2) {
            int idx = r2 * 256 + tid;
            gload16(Ag + (size_t)(bm + (idx >> 3)) * 1024 + k0 + (idx & 7) * 8,
                    (char*)Als + (size_t)(r2 * 256 + w * 64) * 16);
        }
        #pragma unroll
        for (int r2 = 0; r2 < 2; ++r2) {
            int idx = r2 * 256 + tid;
            gload16(Bg + (size_t)(bn + (idx >> 3)) * 1024 + k0 + (idx & 7) * 8,
                    (char*)Bls + (size_t)(r2 * 256 + w * 64) * 16);
        }
        __syncthreads();
        #pragma unroll
        for (int kc = 0; kc < 2; ++kc) {
            f16x8 af[4], bf[2];
            #pragma unroll
            for (int mi = 0; mi < 4; ++mi)
                af[mi] = *reinterpret_cast<const f16x8*>(
                    &Als[(wm * 64 + 16 * mi + a) * 64 + kc * 32 + g * 8]);
            #pragma unroll
            for (int ni = 0; ni < 2; ++ni)
                bf[ni] = *reinterpret_cast<const f16x8*>(
                    &Bls[(wn * 32 + 16 * ni + a) * 64 + kc * 32 + g * 8]);
            #pragma unroll
            for (int mi = 0; mi < 4; ++mi)
                #pragma unroll
                for (int ni = 0; ni < 2; ++ni)
                    acc[mi][ni] = __builtin_amdgcn_mfma_f32_16x16x32_f16(
                        af[mi], bf[ni], acc[mi][ni], 0, 0, 0);
        }
        __syncthreads();
    }

    void* mydst = (mode == 3) ? dst_base
                 : (void*)((unsigned short*)dst_base + (size_t)z * 4194304);

    #pragma unroll
    for (int ni = 0; ni < 2; ++ni) {
        const int n = bn + wn * 32 + 16 * ni + a;
        const float bv = bias[n];
        #pragma unroll
        for (int mi = 0; mi < 4; ++mi) {
            const int mbase = bm + wm * 64 + 16 * mi + g * 4;
            if (mode == 3) {
                float* o = (float*)mydst;
                #pragma unroll
                for (int r = 0; r < 4; ++r)
                    o[(size_t)(mbase + r) * 1024 + n] = acc[mi][ni][r] + bv;
            } else if (mode == 2) {
                unsigned short* o = (unsigned short*)mydst;
                const int b = mbase >> 11, s = mbase & (S_LEN - 1);
                const int h = n >> 6, d = n & (DK - 1);
                ushort4 st;
                st.x = f2h(acc[mi][ni][0] + bv);
                st.y = f2h(acc[mi][ni][1] + bv);
                st.z = f2h(acc[mi][ni][2] + bv);
                st.w = f2h(acc[mi][ni][3] + bv);
                *reinterpret_cast<ushort4*>(
                    o + ((size_t)((b * NHEADS + h) * DK + d)) * S_LEN + s) = st;
            } else {
                unsigned short* o = (unsigned short*)mydst;
                const float sc = (mode == 0) ? QSCALE : 1.0f;
                #pragma unroll
                for (int r = 0; r < 4; ++r) {
                    const int m = mbase + r;
                    const int b = m >> 11, s = m & (S_LEN - 1);
                    const int h = n >> 6, d = n & (DK - 1);
                    o[((size_t)((b * NHEADS + h) * S_LEN + s)) * DK + d] =
                        f2h((acc[mi][ni][r] + bv) * sc);
                }
            }
        }
    }
}

// ---------------------------------------------------------------------------
// MFMA flash attention v4: split-KV, 512 threads / 8 waves.
// Waves w (0-3) and w+4 own the SAME 32 q rows but opposite-parity KV tiles;
// partials (m, l, O) merged exactly at the end via LDS.
// l is accumulated on the MFMA pipe via an all-ones A-fragment (row-sum of P).
// Defer-max: cheap per-lane test; cross-lane reduce+rescale only on fail.
// ---------------------------------------------------------------------------
__global__ __launch_bounds__(512, 4)
void attn_mfma_kernel(const unsigned short* __restrict__ qb,
                      const unsigned short* __restrict__ kb,
                      const unsigned short* __restrict__ vt,
                      unsigned short* __restrict__ ob)
{
    __shared__ char Kls[2][8192];
    __shared__ char Vls[2][8192];
    __shared__ unsigned short Pl[8][32][72];

    const int tid = threadIdx.x;
    const int w = tid >> 6;          // 0..7
    const int p = w >> 2;            // kv parity of this wave
    const int wsub = w & 3;
    const int l = tid & 63;
    const int a = l & 15;
    const int g = l >> 4;
    const int bh = blockIdx.y;
    const int q0 = blockIdx.x * 128 + wsub * 32;

    const unsigned short* qhead = qb + (size_t)bh * S_LEN * DK;
    const char* khead = (const char*)(kb + (size_t)bh * S_LEN * DK);
    const char* vhead = (const char*)(vt + (size_t)bh * DK * S_LEN);

    // Q fragments (pre-scaled by 1/sqrt(dk)*log2e): [q-group j][k-chunk c]
    f16x8 qf[2][2];
    #pragma unroll
    for (int j = 0; j < 2; ++j)
        #pragma unroll
        for (int c = 0; c < 2; ++c)
            qf[j][c] = *reinterpret_cast<const f16x8*>(
                qhead + (size_t)(q0 + 16 * j + a) * DK + 32 * c + 8 * g);

    f16x8 onesf;
    #pragma unroll
    for (int i = 0; i < 8; ++i) onesf[i] = (_Float16)1.f;

    f32x4 oacc[4][2] = {};
    f32x4 lacc[2] = {};
    float mrun[2] = {-INFINITY, -INFINITY};

    // staging geometry: 512 threads x 16 B = one full 64x128B tile per call
    const int srow = tid >> 3;                                  // 0..63
    const int sgc = ((tid & 7) << 4) ^ ((srow & 7) << 4);       // swizzled col

    #define STAGE1(t2)                                                          \
        do {                                                                    \
            gload16(khead + (size_t)((t2) * 64 + srow) * 128 + sgc,             \
                    &Kls[(t2) & 1][(size_t)w * 1024]);                          \
            gload16(vhead + (size_t)srow * 4096 + (size_t)(t2) * 128 + sgc,     \
                    &Vls[(t2) & 1][(size_t)w * 1024]);                          \
        } while (0)

    STAGE1(0);
    STAGE1(1);
    __syncthreads();

    for (int i = 0; i < 16; ++i) {
        // ---- K fragments from buf[p] ----
        f16x8 kf[2][4];
        #pragma unroll
        for (int c = 0; c < 2; ++c)
            #pragma unroll
            for (int T = 0; T < 4; ++T) {
                const int row = 16 * T + a;
                kf[c][T] = *reinterpret_cast<const f16x8*>(
                    &Kls[p][row * 128 + ((64 * c + 16 * g) ^ ((row & 7) << 4))]);
            }

        // ---- per q-group: QK^T burst then softmax (keeps sacc lifetime short)
        #pragma unroll
        for (int j = 0; j < 2; ++j) {
            f32x4 sacc[4] = {};
            __builtin_amdgcn_s_setprio(1);
            #pragma unroll
            for (int c = 0; c < 2; ++c)
                #pragma unroll
                for (int T = 0; T < 4; ++T)
                    sacc[T] = __builtin_amdgcn_mfma_f32_16x16x32_f16(
                        kf[c][T], qf[j][c], sacc[T], 0, 0, 0);
            __builtin_amdgcn_s_setprio(0);

            float lm = -INFINITY;
            #pragma unroll
            for (int T = 0; T < 4; ++T)
                #pragma unroll
                for (int r = 0; r < 4; ++r) lm = fmaxf(lm, sacc[T][r]);

            if (!__all(lm <= mrun[j] + 8.f)) {
                float vmax = fmaxf(lm, __shfl_xor(lm, 16));
                vmax = fmaxf(vmax, __shfl_xor(vmax, 32));
                const float mnew = fmaxf(mrun[j], vmax);
                const float corr = __builtin_amdgcn_exp2f(mrun[j] - mnew);
                #pragma unroll
                for (int t = 0; t < 4; ++t) {
                    oacc[t][j][0] *= corr; oacc[t][j][1] *= corr;
                    oacc[t][j][2] *= corr; oacc[t][j][3] *= corr;
                }
                lacc[j][0] *= corr; lacc[j][1] *= corr;
                lacc[j][2] *= corr; lacc[j][3] *= corr;
                mrun[j] = mnew;
            }

            const float mj = mrun[j];
            #pragma unroll
            for (int T = 0; T < 4; ++T) {
                float e0 = __builtin_amdgcn_exp2f(sacc[T][0] - mj);
                float e1 = __builtin_amdgcn_exp2f(sacc[T][1] - mj);
                float e2 = __builtin_amdgcn_exp2f(sacc[T][2] - mj);
                float e3 = __builtin_amdgcn_exp2f(sacc[T][3] - mj);
                unsigned* dst = reinterpret_cast<unsigned*>(
                    &Pl[w][16 * j + a][16 * T + 4 * g]);
                dst[0] = pack2(e0, e1);
                dst[1] = pack2(e2, e3);
            }
        }

        // ---- V fragments from buf[p] (must precede barrier) ----
        f16x8 vf[2][4];
        #pragma unroll
        for (int c = 0; c < 2; ++c)
            #pragma unroll
            for (int t = 0; t < 4; ++t) {
                const int row = 16 * t + a;
                vf[c][t] = *reinterpret_cast<const f16x8*>(
                    &Vls[p][row * 128 + ((64 * c + 16 * g) ^ ((row & 7) << 4))]);
            }

        __syncthreads();                       // all buf reads complete
        if (i < 15) {
            STAGE1(2 * i + 2);                 // prefetch both parities
            STAGE1(2 * i + 3);
        }

        // ---- PV + ones-row l accumulation ----
        #pragma unroll
        for (int c = 0; c < 2; ++c) {
            f16x8 pf[2];
            #pragma unroll
            for (int j = 0; j < 2; ++j)
                pf[j] = *reinterpret_cast<const f16x8*>(
                    &Pl[w][16 * j + a][32 * c + 8 * g]);
            __builtin_amdgcn_s_setprio(1);
            #pragma unroll
            for (int t = 0; t < 4; ++t)
                #pragma unroll
                for (int j = 0; j < 2; ++j)
                    oacc[t][j] = __builtin_amdgcn_mfma_f32_16x16x32_f16(
                        vf[c][t], pf[j], oacc[t][j], 0, 0, 0);
            #pragma unroll
            for (int j = 0; j < 2; ++j)
                lacc[j] = __builtin_amdgcn_mfma_f32_16x16x32_f16(
                    onesf, pf[j], lacc[j], 0, 0, 0);
            __builtin_amdgcn_s_setprio(0);
        }
        __syncthreads();                       // staged loads drained (vmcnt)
    }
    #undef STAGE1

    // ---- merge partials between wave pairs (w, w+4) ----
    float* Ob = (float*)Pl;                    // 36864 B >= 32768 needed
    float* Ml = (float*)Kls;                   // 1 KB for m,l
    if (p == 1) {
        #pragma unroll
        for (int j = 0; j < 2; ++j) {
            if (g == 0) {
                Ml[((wsub * 2 + j) * 2 + 0) * 16 + a] = mrun[j];
                Ml[((wsub * 2 + j) * 2 + 1) * 16 + a] = lacc[j][0];
            }
            #pragma unroll
            for (int t = 0; t < 4; ++t)
                #pragma unroll
                for (int r = 0; r < 4; ++r)
                    Ob[((wsub * 2 + j) * 64 + 16 * t + 4 * g + r) * 16 + a] =
                        oacc[t][j][r];
        }
    }
    __syncthreads();
    if (p == 0) {
        const int b = bh >> 4;
        const int h = bh & (NHEADS - 1);
        #pragma unroll
        for (int j = 0; j < 2; ++j) {
            const float m1 = Ml[((wsub * 2 + j) * 2 + 0) * 16 + a];
            const float l1 = Ml[((wsub * 2 + j) * 2 + 1) * 16 + a];
            const float m0 = mrun[j];
            const float ms = fmaxf(m0, m1);
            const float c0 = __builtin_amdgcn_exp2f(m0 - ms);
            const float c1 = __builtin_amdgcn_exp2f(m1 - ms);
            const float inv = 1.f / (lacc[j][0] * c0 + l1 * c1);
            unsigned short* dst0 =
                ob + (size_t)(b * S_LEN + q0 + 16 * j + a) * DMODEL + h * DK;
            #pragma unroll
            for (int t = 0; t < 4; ++t) {
                ushort4 st;
                #pragma unroll
                for (int r = 0; r < 4; ++r) {
                    const float o1 =
                        Ob[((wsub * 2 + j) * 64 + 16 * t + 4 * g + r) * 16 + a];
                    const float val = (oacc[t][j][r] * c0 + o1 * c1) * inv;
                    ((unsigned short*)&st)[r] = f2h(val);
                }
                *reinterpret_cast<ushort4*>(dst0 + 16 * t + 4 * g) = st;
            }
        }
    }
}

// ---------------------------------------------------------------------------
extern "C" void kernel_launch(void* const* d_in, const int* in_sizes, int n_in,
                              void* d_out, int out_size, void* d_ws, size_t ws_size,
                              hipStream_t stream)
{
    const float* Q  = (const float*)d_in[0];
    const float* K  = (const float*)d_in[1];
    const float* V  = (const float*)d_in[2];
    const float* Wq = (const float*)d_in[3];
    const float* bq = (const float*)d_in[4];
    const float* Wk = (const float*)d_in[5];
    const float* bk = (const float*)d_in[6];
    const float* Wv = (const float*)d_in[7];
    const float* bv = (const float*)d_in[8];
    const float* Wo = (const float*)d_in[9];
    const float* bo = (const float*)d_in[10];
    float* out = (float*)d_out;

    // ws layout (fp16 elems): xh[3*4M] wt[4*1M] qb[4M] kb[4M] vtb[4M] ob[4M]
    unsigned short* xh  = (unsigned short*)d_ws;
    unsigned short* wt  = xh + (size_t)3 * 4194304;
    unsigned short* qb  = wt + (size_t)4 * 1048576;
    unsigned short* kb  = qb + 4194304;
    unsigned short* vtb = kb + 4194304;
    unsigned short* obh = vtb + 4194304;

    cvt_f16_kernel<<<dim3(2048, 3), 256, 0, stream>>>(Q, K, V, xh);
    wprep_kernel<<<dim3(16, 16, 4), 256, 0, stream>>>(Wq, Wk, Wv, Wo, wt);

    gemm_mfma_kernel<<<dim3(32, 16, 3), 256, 0, stream>>>(
        xh, wt, bq, bk, bv, qb, -1);

    attn_mfma_kernel<<<dim3(S_LEN / 128, 2 * NHEADS), 512, 0, stream>>>(qb, kb, vtb, obh);

    gemm_mfma_kernel<<<dim3(32, 16, 1), 256, 0, stream>>>(
        obh, wt + (size_t)3 * 1048576, bo, bo, bo, out, 3);
}

// Round 13
// 137.129 us; speedup vs baseline: 18.6951x; 1.0002x over previous
//
#include <hip/hip_runtime.h>
#include <math.h>

#define S_LEN 2048
#define DMODEL 1024
#define NHEADS 16
#define DK 64

// q-projection scale: 1/sqrt(dk) * log2(e)  -> softmax works in exp2 domain
#define QSCALE 0.1803368801111244f

typedef __attribute__((ext_vector_type(8))) _Float16 f16x8;
typedef __attribute__((ext_vector_type(2))) __fp16 hf16x2;
typedef __attribute__((ext_vector_type(4))) float f32x4;

static __device__ __forceinline__ unsigned short f2h(float f) {
    _Float16 h = (_Float16)f;
    return __builtin_bit_cast(unsigned short, h);
}

static __device__ __forceinline__ unsigned pack2(float a, float b) {
    hf16x2 h = __builtin_amdgcn_cvt_pkrtz(a, b);
    return __builtin_bit_cast(unsigned, h);
}

static __device__ __forceinline__ void gload16(const void* g, void* l) {
    __builtin_amdgcn_global_load_lds(
        (const __attribute__((address_space(1))) void*)g,
        (__attribute__((address_space(3))) void*)l, 16, 0, 0);
}

// ---------------------------------------------------------------------------
// fp32 -> fp16 elementwise convert for Q, K, V inputs (z selects tensor).
// ---------------------------------------------------------------------------
__global__ __launch_bounds__(256)
void cvt_f16_kernel(const float* __restrict__ s0, const float* __restrict__ s1,
                    const float* __restrict__ s2, unsigned short* __restrict__ d)
{
    const int z = blockIdx.y;
    const float* src = z == 0 ? s0 : (z == 1 ? s1 : s2);
    unsigned short* dst = d + (size_t)z * 4194304;
    const int i = (blockIdx.x * 256 + threadIdx.x) * 8;
    float4 a = *reinterpret_cast<const float4*>(src + i);
    float4 b = *reinterpret_cast<const float4*>(src + i + 4);
    uint4 o;
    o.x = pack2(a.x, a.y);
    o.y = pack2(a.z, a.w);
    o.z = pack2(b.x, b.y);
    o.w = pack2(b.z, b.w);
    *reinterpret_cast<uint4*>(dst + i) = o;
}

// ---------------------------------------------------------------------------
// W [1024][1024] fp32 -> Wt [n][k] fp16 (transposed), LDS-tiled 64x64.
// ---------------------------------------------------------------------------
__global__ __launch_bounds__(256)
void wprep_kernel(const float* __restrict__ w0, const float* __restrict__ w1,
                  const float* __restrict__ w2, const float* __restrict__ w3,
                  unsigned short* __restrict__ wt)
{
    __shared__ float tile[64][65];
    const int z = blockIdx.z;
    const float* W = z == 0 ? w0 : (z == 1 ? w1 : (z == 2 ? w2 : w3));
    unsigned short* Wt = wt + (size_t)z * 1048576;
    const int k0 = blockIdx.x * 64, n0 = blockIdx.y * 64;
    const int t = threadIdx.x;
    #pragma unroll
    for (int i = 0; i < 4; ++i) {
        int idx = i * 256 + t;
        int r = idx >> 4, c4 = (idx & 15) * 4;
        float4 v = *reinterpret_cast<const float4*>(W + (size_t)(k0 + r) * 1024 + n0 + c4);
        tile[r][c4 + 0] = v.x; tile[r][c4 + 1] = v.y;
        tile[r][c4 + 2] = v.z; tile[r][c4 + 3] = v.w;
    }
    __syncthreads();
    #pragma unroll
    for (int i = 0; i < 4; ++i) {
        int idx = i * 256 + t;
        int nr = idx >> 4, kc4 = (idx & 15) * 4;
        ushort4 h;
        h.x = f2h(tile[kc4 + 0][nr]); h.y = f2h(tile[kc4 + 1][nr]);
        h.z = f2h(tile[kc4 + 2][nr]); h.w = f2h(tile[kc4 + 3][nr]);
        *reinterpret_cast<ushort4*>(Wt + (size_t)(n0 + nr) * 1024 + k0 + kc4) = h;
    }
}

// ---------------------------------------------------------------------------
// MFMA fp16 GEMM v2: tile 128x128, 512 thr / 8 waves (2x4), BK=64,
// XOR-swizzled LDS (pre-swizzled global source + linear gload_lds dest),
// grid (N/128=8, M/128=32, z) so consecutive blocks share the A-tile and
// each XCD keeps its W column-slab L2-resident.
// mode 0: q (scaled QSCALE) / 1: k / 2: v transposed / 3: fp32 row-major out
// ---------------------------------------------------------------------------
__global__ __launch_bounds__(512)
void gemm_mfma_kernel(const unsigned short* __restrict__ xh_base,
                      const unsigned short* __restrict__ wt_base,
                      const float* __restrict__ b0, const float* __restrict__ b1,
                      const float* __restrict__ b2,
                      void* __restrict__ dst_base, int mode_base)
{
    __shared__ char Als[16384];   // 128 rows x 64 k fp16, swizzled
    __shared__ char Bls[16384];   // 128 n   x 64 k fp16, swizzled

    const int z = blockIdx.z;
    const char* Ag = (const char*)(xh_base + (size_t)z * 4194304);
    const char* Bg = (const char*)(wt_base + (size_t)z * 1048576);
    const float* bias = z == 0 ? b0 : (z == 1 ? b1 : b2);
    const int mode = mode_base < 0 ? z : mode_base;

    const int tid = threadIdx.x;
    const int w = tid >> 6, l = tid & 63, a = l & 15, g = l >> 4;
    const int wm = w >> 2, wn = w & 3;            // 2 x 4 wave grid
    const int bm = blockIdx.y * 128, bn = blockIdx.x * 128;

    const int srow = tid >> 3;                    // 0..63 (it adds 64)
    const int sc8 = tid & 7;

    f32x4 acc[4][2] = {};

    for (int k0b = 0; k0b < 2048; k0b += 128) {   // K bytes per row
        #pragma unroll
        for (int it = 0; it < 2; ++it) {
            const int row = it * 64 + srow;
            const int gc = (sc8 << 4) ^ ((row & 7) << 4);
            gload16(Ag + (size_t)(bm + row) * 2048 + k0b + gc,
                    &Als[(size_t)(it * 512 + tid) * 16]);
            gload16(Bg + (size_t)(bn + row) * 2048 + k0b + gc,
                    &Bls[(size_t)(it * 512 + tid) * 16]);
        }
        __syncthreads();
        #pragma unroll
        for (int kc = 0; kc < 2; ++kc) {
            f16x8 af[4], bf[2];
            #pragma unroll
            for (int mi = 0; mi < 4; ++mi) {
                const int row = wm * 64 + 16 * mi + a;
                af[mi] = *reinterpret_cast<const f16x8*>(
                    &Als[row * 128 + ((kc * 64 + g * 16) ^ ((row & 7) << 4))]);
            }
            #pragma unroll
            for (int ni = 0; ni < 2; ++ni) {
                const int row = wn * 32 + 16 * ni + a;
                bf[ni] = *reinterpret_cast<const f16x8*>(
                    &Bls[row * 128 + ((kc * 64 + g * 16) ^ ((row & 7) << 4))]);
            }
            __builtin_amdgcn_s_setprio(1);
            #pragma unroll
            for (int mi = 0; mi < 4; ++mi)
                #pragma unroll
                for (int ni = 0; ni < 2; ++ni)
                    acc[mi][ni] = __builtin_amdgcn_mfma_f32_16x16x32_f16(
                        af[mi], bf[ni], acc[mi][ni], 0, 0, 0);
            __builtin_amdgcn_s_setprio(0);
        }
        __syncthreads();
    }

    void* mydst = (mode == 3) ? dst_base
                 : (void*)((unsigned short*)dst_base + (size_t)z * 4194304);

    #pragma unroll
    for (int ni = 0; ni < 2; ++ni) {
        const int n = bn + wn * 32 + 16 * ni + a;
        const float bv = bias[n];
        #pragma unroll
        for (int mi = 0; mi < 4; ++mi) {
            const int mbase = bm + wm * 64 + 16 * mi + g * 4;
            if (mode == 3) {
                float* o = (float*)mydst;
                #pragma unroll
                for (int r = 0; r < 4; ++r)
                    o[(size_t)(mbase + r) * 1024 + n] = acc[mi][ni][r] + bv;
            } else if (mode == 2) {
                unsigned short* o = (unsigned short*)mydst;
                const int b = mbase >> 11, s = mbase & (S_LEN - 1);
                const int h = n >> 6, d = n & (DK - 1);
                ushort4 st;
                st.x = f2h(acc[mi][ni][0] + bv);
                st.y = f2h(acc[mi][ni][1] + bv);
                st.z = f2h(acc[mi][ni][2] + bv);
                st.w = f2h(acc[mi][ni][3] + bv);
                *reinterpret_cast<ushort4*>(
                    o + ((size_t)((b * NHEADS + h) * DK + d)) * S_LEN + s) = st;
            } else {
                unsigned short* o = (unsigned short*)mydst;
                const float sc = (mode == 0) ? QSCALE : 1.0f;
                #pragma unroll
                for (int r = 0; r < 4; ++r) {
                    const int m = mbase + r;
                    const int b = m >> 11, s = m & (S_LEN - 1);
                    const int h = n >> 6, d = n & (DK - 1);
                    o[((size_t)((b * NHEADS + h) * S_LEN + s)) * DK + d] =
                        f2h((acc[mi][ni][r] + bv) * sc);
                }
            }
        }
    }
}

// ---------------------------------------------------------------------------
// MFMA flash attention v4: split-KV, 512 threads / 8 waves.
// Waves w (0-3) and w+4 own the SAME 32 q rows but opposite-parity KV tiles;
// partials (m, l, O) merged exactly at the end via LDS.
// l is accumulated on the MFMA pipe via an all-ones A-fragment (row-sum of P).
// Defer-max: cheap per-lane test; cross-lane reduce+rescale only on fail.
// ---------------------------------------------------------------------------
__global__ __launch_bounds__(512, 4)
void attn_mfma_kernel(const unsigned short* __restrict__ qb,
                      const unsigned short* __restrict__ kb,
                      const unsigned short* __restrict__ vt,
                      unsigned short* __restrict__ ob)
{
    __shared__ char Kls[2][8192];
    __shared__ char Vls[2][8192];
    __shared__ unsigned short Pl[8][32][72];

    const int tid = threadIdx.x;
    const int w = tid >> 6;          // 0..7
    const int p = w >> 2;            // kv parity of this wave
    const int wsub = w & 3;
    const int l = tid & 63;
    const int a = l & 15;
    const int g = l >> 4;
    const int bh = blockIdx.y;
    const int q0 = blockIdx.x * 128 + wsub * 32;

    const unsigned short* qhead = qb + (size_t)bh * S_LEN * DK;
    const char* khead = (const char*)(kb + (size_t)bh * S_LEN * DK);
    const char* vhead = (const char*)(vt + (size_t)bh * DK * S_LEN);

    // Q fragments (pre-scaled by 1/sqrt(dk)*log2e): [q-group j][k-chunk c]
    f16x8 qf[2][2];
    #pragma unroll
    for (int j = 0; j < 2; ++j)
        #pragma unroll
        for (int c = 0; c < 2; ++c)
            qf[j][c] = *reinterpret_cast<const f16x8*>(
                qhead + (size_t)(q0 + 16 * j + a) * DK + 32 * c + 8 * g);

    f16x8 onesf;
    #pragma unroll
    for (int i = 0; i < 8; ++i) onesf[i] = (_Float16)1.f;

    f32x4 oacc[4][2] = {};
    f32x4 lacc[2] = {};
    float mrun[2] = {-INFINITY, -INFINITY};

    // staging geometry: 512 threads x 16 B = one full 64x128B tile per call
    const int srow = tid >> 3;                                  // 0..63
    const int sgc = ((tid & 7) << 4) ^ ((srow & 7) << 4);       // swizzled col

    #define STAGE1(t2)                                                          \
        do {                                                                    \
            gload16(khead + (size_t)((t2) * 64 + srow) * 128 + sgc,             \
                    &Kls[(t2) & 1][(size_t)w * 1024]);                          \
            gload16(vhead + (size_t)srow * 4096 + (size_t)(t2) * 128 + sgc,     \
                    &Vls[(t2) & 1][(size_t)w * 1024]);                          \
        } while (0)

    STAGE1(0);
    STAGE1(1);
    __syncthreads();

    for (int i = 0; i < 16; ++i) {
        // ---- K fragments from buf[p] ----
        f16x8 kf[2][4];
        #pragma unroll
        for (int c = 0; c < 2; ++c)
            #pragma unroll
            for (int T = 0; T < 4; ++T) {
                const int row = 16 * T + a;
                kf[c][T] = *reinterpret_cast<const f16x8*>(
                    &Kls[p][row * 128 + ((64 * c + 16 * g) ^ ((row & 7) << 4))]);
            }

        // ---- per q-group: QK^T burst then softmax (keeps sacc lifetime short)
        #pragma unroll
        for (int j = 0; j < 2; ++j) {
            f32x4 sacc[4] = {};
            __builtin_amdgcn_s_setprio(1);
            #pragma unroll
            for (int c = 0; c < 2; ++c)
                #pragma unroll
                for (int T = 0; T < 4; ++T)
                    sacc[T] = __builtin_amdgcn_mfma_f32_16x16x32_f16(
                        kf[c][T], qf[j][c], sacc[T], 0, 0, 0);
            __builtin_amdgcn_s_setprio(0);

            float lm = -INFINITY;
            #pragma unroll
            for (int T = 0; T < 4; ++T)
                #pragma unroll
                for (int r = 0; r < 4; ++r) lm = fmaxf(lm, sacc[T][r]);

            if (!__all(lm <= mrun[j] + 8.f)) {
                float vmax = fmaxf(lm, __shfl_xor(lm, 16));
                vmax = fmaxf(vmax, __shfl_xor(vmax, 32));
                const float mnew = fmaxf(mrun[j], vmax);
                const float corr = __builtin_amdgcn_exp2f(mrun[j] - mnew);
                #pragma unroll
                for (int t = 0; t < 4; ++t) {
                    oacc[t][j][0] *= corr; oacc[t][j][1] *= corr;
                    oacc[t][j][2] *= corr; oacc[t][j][3] *= corr;
                }
                lacc[j][0] *= corr; lacc[j][1] *= corr;
                lacc[j][2] *= corr; lacc[j][3] *= corr;
                mrun[j] = mnew;
            }

            const float mj = mrun[j];
            #pragma unroll
            for (int T = 0; T < 4; ++T) {
                float e0 = __builtin_amdgcn_exp2f(sacc[T][0] - mj);
                float e1 = __builtin_amdgcn_exp2f(sacc[T][1] - mj);
                float e2 = __builtin_amdgcn_exp2f(sacc[T][2] - mj);
                float e3 = __builtin_amdgcn_exp2f(sacc[T][3] - mj);
                unsigned* dst = reinterpret_cast<unsigned*>(
                    &Pl[w][16 * j + a][16 * T + 4 * g]);
                dst[0] = pack2(e0, e1);
                dst[1] = pack2(e2, e3);
            }
        }

        // ---- V fragments from buf[p] (must precede barrier) ----
        f16x8 vf[2][4];
        #pragma unroll
        for (int c = 0; c < 2; ++c)
            #pragma unroll
            for (int t = 0; t < 4; ++t) {
                const int row = 16 * t + a;
                vf[c][t] = *reinterpret_cast<const f16x8*>(
                    &Vls[p][row * 128 + ((64 * c + 16 * g) ^ ((row & 7) << 4))]);
            }

        __syncthreads();                       // all buf reads complete
        if (i < 15) {
            STAGE1(2 * i + 2);                 // prefetch both parities
            STAGE1(2 * i + 3);
        }

        // ---- PV + ones-row l accumulation ----
        #pragma unroll
        for (int c = 0; c < 2; ++c) {
            f16x8 pf[2];
            #pragma unroll
            for (int j = 0; j < 2; ++j)
                pf[j] = *reinterpret_cast<const f16x8*>(
                    &Pl[w][16 * j + a][32 * c + 8 * g]);
            __builtin_amdgcn_s_setprio(1);
            #pragma unroll
            for (int t = 0; t < 4; ++t)
                #pragma unroll
                for (int j = 0; j < 2; ++j)
                    oacc[t][j] = __builtin_amdgcn_mfma_f32_16x16x32_f16(
                        vf[c][t], pf[j], oacc[t][j], 0, 0, 0);
            #pragma unroll
            for (int j = 0; j < 2; ++j)
                lacc[j] = __builtin_amdgcn_mfma_f32_16x16x32_f16(
                    onesf, pf[j], lacc[j], 0, 0, 0);
            __builtin_amdgcn_s_setprio(0);
        }
        __syncthreads();                       // staged loads drained (vmcnt)
    }
    #undef STAGE1

    // ---- merge partials between wave pairs (w, w+4) ----
    float* Ob = (float*)Pl;                    // 36864 B >= 32768 needed
    float* Ml = (float*)Kls;                   // 1 KB for m,l
    if (p == 1) {
        #pragma unroll
        for (int j = 0; j < 2; ++j) {
            if (g == 0) {
                Ml[((wsub * 2 + j) * 2 + 0) * 16 + a] = mrun[j];
                Ml[((wsub * 2 + j) * 2 + 1) * 16 + a] = lacc[j][0];
            }
            #pragma unroll
            for (int t = 0; t < 4; ++t)
                #pragma unroll
                for (int r = 0; r < 4; ++r)
                    Ob[((wsub * 2 + j) * 64 + 16 * t + 4 * g + r) * 16 + a] =
                        oacc[t][j][r];
        }
    }
    __syncthreads();
    if (p == 0) {
        const int b = bh >> 4;
        const int h = bh & (NHEADS - 1);
        #pragma unroll
        for (int j = 0; j < 2; ++j) {
            const float m1 = Ml[((wsub * 2 + j) * 2 + 0) * 16 + a];
            const float l1 = Ml[((wsub * 2 + j) * 2 + 1) * 16 + a];
            const float m0 = mrun[j];
            const float ms = fmaxf(m0, m1);
            const float c0 = __builtin_amdgcn_exp2f(m0 - ms);
            const float c1 = __builtin_amdgcn_exp2f(m1 - ms);
            const float inv = 1.f / (lacc[j][0] * c0 + l1 * c1);
            unsigned short* dst0 =
                ob + (size_t)(b * S_LEN + q0 + 16 * j + a) * DMODEL + h * DK;
            #pragma unroll
            for (int t = 0; t < 4; ++t) {
                ushort4 st;
                #pragma unroll
                for (int r = 0; r < 4; ++r) {
                    const float o1 =
                        Ob[((wsub * 2 + j) * 64 + 16 * t + 4 * g + r) * 16 + a];
                    const float val = (oacc[t][j][r] * c0 + o1 * c1) * inv;
                    ((unsigned short*)&st)[r] = f2h(val);
                }
                *reinterpret_cast<ushort4*>(dst0 + 16 * t + 4 * g) = st;
            }
        }
    }
}

// ---------------------------------------------------------------------------
extern "C" void kernel_launch(void* const* d_in, const int* in_sizes, int n_in,
                              void* d_out, int out_size, void* d_ws, size_t ws_size,
                              hipStream_t stream)
{
    const float* Q  = (const float*)d_in[0];
    const float* K  = (const float*)d_in[1];
    const float* V  = (const float*)d_in[2];
    const float* Wq = (const float*)d_in[3];
    const float* bq = (const float*)d_in[4];
    const float* Wk = (const float*)d_in[5];
    const float* bk = (const float*)d_in[6];
    const float* Wv = (const float*)d_in[7];
    const float* bv = (const float*)d_in[8];
    const float* Wo = (const float*)d_in[9];
    const float* bo = (const float*)d_in[10];
    float* out = (float*)d_out;

    // ws layout (fp16 elems): xh[3*4M] wt[4*1M] qb[4M] kb[4M] vtb[4M] ob[4M]
    unsigned short* xh  = (unsigned short*)d_ws;
    unsigned short* wt  = xh + (size_t)3 * 4194304;
    unsigned short* qb  = wt + (size_t)4 * 1048576;
    unsigned short* kb  = qb + 4194304;
    unsigned short* vtb = kb + 4194304;
    unsigned short* obh = vtb + 4194304;

    cvt_f16_kernel<<<dim3(2048, 3), 256, 0, stream>>>(Q, K, V, xh);
    wprep_kernel<<<dim3(16, 16, 4), 256, 0, stream>>>(Wq, Wk, Wv, Wo, wt);

    // q/k/v projections (z-fused): modes 0,1,2 ; grid (N/128, M/128, 3)
    gemm_mfma_kernel<<<dim3(8, 32, 3), 512, 0, stream>>>(
        xh, wt, bq, bk, bv, qb, -1);

    attn_mfma_kernel<<<dim3(S_LEN / 128, 2 * NHEADS), 512, 0, stream>>>(qb, kb, vtb, obh);

    // output projection: mode 3
    gemm_mfma_kernel<<<dim3(8, 32, 1), 512, 0, stream>>>(
        obh, wt + (size_t)3 * 1048576, bo, bo, bo, out, 3);
}